// Round 1
// baseline (346.877 us; speedup 1.0000x reference)
//
#include <hip/hip_runtime.h>

// ---------------------------------------------------------------------------
// FeatureNet: kNN(K=8) relative grouping -> [conv1x1+BN+ReLU] x3 -> max over K
// B=8, N=2048, DIM=128, fp32.
//
// Pipeline:
//   prep    : fold BN into weights/biases  (W0f,c0,W1f,c1,W2f,c2)
//   ycomp   : y[q][f] = W0f . x[q]      (layer0 matvec, pairless)
//   knn_part: per (batch, query-tile, cand-range) top-8   (4 ranges of 512)
//   knn_mrg : merge 4 partial top-8 lists -> idx[q][8]
//   gemm1   : h2 = relu(W1f . relu(y_m - y_n + c0) + c1)  (131072 x 128)
//   gemm2   : h3 = relu(W2f . h2 + c2); out = max over k  (write [B,128,N])
// ---------------------------------------------------------------------------

#define EPSF 1e-5f
#define FMAXV 3.402823466e+38f

#define NB 8
#define NN 2048
#define KNBR 8
#define DIMF 128
#define NQ (NB * NN)        // 16384 queries
#define NPAIR (NQ * KNBR)   // 131072 pairs

// ws layout (float offsets)
#define OFF_W1F   0                       // 16384
#define OFF_W2F   16384                   // 16384
#define OFF_C0    32768                   // 128
#define OFF_C1    32896                   // 128
#define OFF_C2    33024                   // 128
#define OFF_W0F   33152                   // 384
#define OFF_PART  34816                   // 16384*32*2 = 1048576 (float2 d,idx)
#define OFF_Y     (OFF_PART + NQ * 64)    // 2097152 floats
#define OFF_IDX   (OFF_Y + NQ * DIMF)     // 131072 ints
#define OFF_H2    (OFF_IDX + NPAIR)       // 16777216 floats
// total ~19.07 M floats = ~72.8 MiB of ws

__device__ __forceinline__ float relu_f(float a) { return fmaxf(a, 0.0f); }

// ------------------------------- prep --------------------------------------
__global__ __launch_bounds__(256) void prep_kernel(
    const float* __restrict__ w0, const float* __restrict__ b0,
    const float* __restrict__ wstk, const float* __restrict__ bstk,
    const float* __restrict__ g, const float* __restrict__ be,
    const float* __restrict__ bm, const float* __restrict__ bv,
    float* __restrict__ ws) {
  const int t = threadIdx.x;
  for (int i = t; i < 16384; i += 256) {
    const int fo = i >> 7;
    const float s1 = g[128 + fo] / sqrtf(bv[128 + fo] + EPSF);
    const float s2 = g[256 + fo] / sqrtf(bv[256 + fo] + EPSF);
    ws[OFF_W1F + i] = wstk[i] * s1;
    ws[OFF_W2F + i] = wstk[16384 + i] * s2;
  }
  if (t < 128) {
    const int fo = t;
    const float s0 = g[fo] / sqrtf(bv[fo] + EPSF);
    const float s1 = g[128 + fo] / sqrtf(bv[128 + fo] + EPSF);
    const float s2 = g[256 + fo] / sqrtf(bv[256 + fo] + EPSF);
    ws[OFF_C0 + fo] = (b0[fo] - bm[fo]) * s0 + be[fo];
    ws[OFF_C1 + fo] = (bstk[fo] - bm[128 + fo]) * s1 + be[128 + fo];
    ws[OFF_C2 + fo] = (bstk[128 + fo] - bm[256 + fo]) * s2 + be[256 + fo];
    ws[OFF_W0F + 3 * fo + 0] = w0[3 * fo + 0] * s0;
    ws[OFF_W0F + 3 * fo + 1] = w0[3 * fo + 1] * s0;
    ws[OFF_W0F + 3 * fo + 2] = w0[3 * fo + 2] * s0;
  }
}

// ------------------------------- ycomp -------------------------------------
__global__ __launch_bounds__(256) void y_kernel(const float* __restrict__ x,
                                                float* __restrict__ ws) {
  const int gid = blockIdx.x * 256 + threadIdx.x;  // 2,097,152
  const int q = gid >> 7, f = gid & 127;
  const int b = q >> 11, n = q & 2047;
  const float* __restrict__ W0f = ws + OFF_W0F;
  const float w0 = W0f[f * 3 + 0], w1 = W0f[f * 3 + 1], w2 = W0f[f * 3 + 2];
  const float x0 = x[b * 6144 + n];
  const float x1 = x[b * 6144 + 2048 + n];
  const float x2 = x[b * 6144 + 4096 + n];
  ws[OFF_Y + gid] = fmaf(w2, x2, fmaf(w1, x1, w0 * x0));
}

// ------------------------------- knn ---------------------------------------
#define KNN_CSWAP(da, db, ia, ib)            \
  {                                          \
    const bool c_ = (db) < (da);             \
    const float lo_ = c_ ? (db) : (da);      \
    const float hi_ = c_ ? (da) : (db);      \
    const int il_ = c_ ? (ib) : (ia);        \
    const int ih_ = c_ ? (ia) : (ib);        \
    (da) = lo_; (db) = hi_;                  \
    (ia) = il_; (ib) = ih_;                  \
  }

#define KNN_INSERT(d, mi)                     \
  if ((d) < b7v) {                            \
    b7v = (d); i7v = (mi);                    \
    KNN_CSWAP(b6v, b7v, i6v, i7v)             \
    KNN_CSWAP(b5v, b6v, i5v, i6v)             \
    KNN_CSWAP(b4v, b5v, i4v, i5v)             \
    KNN_CSWAP(b3v, b4v, i3v, i4v)             \
    KNN_CSWAP(b2v, b3v, i2v, i3v)             \
    KNN_CSWAP(b1v, b2v, i1v, i2v)             \
    KNN_CSWAP(b0v, b1v, i0v, i1v)             \
  }

// wg = b*32 + qtile*4 + range ; 256 threads = 256 queries; 512 candidates
__global__ __launch_bounds__(256) void knn_part_kernel(
    const float* __restrict__ x, float* __restrict__ ws) {
  __shared__ float4 xs4[512];
  const int t = threadIdx.x;
  const int wg = blockIdx.x;
  const int b = wg >> 5, qt = (wg >> 2) & 7, r = wg & 3;
  const float* __restrict__ xb = x + b * 3 * NN;
  for (int i = t; i < 512; i += 256) {
    const float a0 = xb[r * 512 + i];
    const float a1 = xb[2048 + r * 512 + i];
    const float a2 = xb[4096 + r * 512 + i];
    const float sq = fmaf(a2, a2, fmaf(a1, a1, a0 * a0));
    xs4[i] = make_float4(a0, a1, a2, sq);
  }
  __syncthreads();
  const int n = qt * 256 + t;
  const float qx0 = xb[n], qx1 = xb[2048 + n], qx2 = xb[4096 + n];
  const float sqn = fmaf(qx2, qx2, fmaf(qx1, qx1, qx0 * qx0));
  float b0v = FMAXV, b1v = FMAXV, b2v = FMAXV, b3v = FMAXV,
        b4v = FMAXV, b5v = FMAXV, b6v = FMAXV, b7v = FMAXV;
  int i0v = 0, i1v = 0, i2v = 0, i3v = 0, i4v = 0, i5v = 0, i6v = 0, i7v = 0;
  const int gbase = b * NN + r * 512;
#pragma unroll 2
  for (int mm = 0; mm < 512; ++mm) {
    const float4 c = xs4[mm];
    const float inner = fmaf(qx2, c.z, fmaf(qx1, c.y, qx0 * c.x));
    const float d = (sqn - 2.0f * inner) + c.w;
    KNN_INSERT(d, gbase + mm)
  }
  float2* __restrict__ part = (float2*)(ws + OFF_PART);
  float2* p = part + (long)(b * NN + n) * 32 + r * 8;
  p[0] = make_float2(b0v, __int_as_float(i0v));
  p[1] = make_float2(b1v, __int_as_float(i1v));
  p[2] = make_float2(b2v, __int_as_float(i2v));
  p[3] = make_float2(b3v, __int_as_float(i3v));
  p[4] = make_float2(b4v, __int_as_float(i4v));
  p[5] = make_float2(b5v, __int_as_float(i5v));
  p[6] = make_float2(b6v, __int_as_float(i6v));
  p[7] = make_float2(b7v, __int_as_float(i7v));
}

__global__ __launch_bounds__(256) void knn_merge_kernel(float* __restrict__ ws) {
  const int q = blockIdx.x * 256 + threadIdx.x;  // 16384
  const float2* __restrict__ part = (const float2*)(ws + OFF_PART);
  float b0v = FMAXV, b1v = FMAXV, b2v = FMAXV, b3v = FMAXV,
        b4v = FMAXV, b5v = FMAXV, b6v = FMAXV, b7v = FMAXV;
  int i0v = 0, i1v = 0, i2v = 0, i3v = 0, i4v = 0, i5v = 0, i6v = 0, i7v = 0;
#pragma unroll 4
  for (int s = 0; s < 32; ++s) {
    const float2 e = part[(long)q * 32 + s];
    const float d = e.x;
    const int mi = __float_as_int(e.y);
    KNN_INSERT(d, mi)
  }
  int* __restrict__ idxg = (int*)(ws + OFF_IDX);
  int* o = idxg + q * 8;
  o[0] = i0v; o[1] = i1v; o[2] = i2v; o[3] = i3v;
  o[4] = i4v; o[5] = i5v; o[6] = i6v; o[7] = i7v;
}

// ------------------------------- gemm1 -------------------------------------
// chunk = 128 pairs. LDS: W (4096 float4, swizzled) + A (4096 float4, swizzled)
// thread t: fo_blk = t&15 (8 feats), pb = t>>4 (4 pairs). acc[4][8].
__global__ __launch_bounds__(512, 2) void gemm1_kernel(float* __restrict__ ws) {
  extern __shared__ float lds[];
  float4* __restrict__ W4 = (float4*)lds;
  float4* __restrict__ A4 = ((float4*)lds) + 4096;
  const float* __restrict__ y = ws + OFF_Y;
  const int* __restrict__ idxg = (const int*)(ws + OFF_IDX);
  float* __restrict__ h2 = ws + OFF_H2;
  const int t = threadIdx.x;

  {  // stage W1f (swizzle 16B chunks by (fo>>3)&7)
    const float4* __restrict__ Wsrc = (const float4*)(ws + OFF_W1F);
#pragma unroll
    for (int j = 0; j < 8; ++j) {
      const int i4 = t + j * 512;
      const int fo = i4 >> 5, k4 = i4 & 31;
      W4[fo * 32 + (k4 ^ ((fo >> 3) & 7))] = Wsrc[i4];
    }
  }

  const int pidx = t >> 2, s = t & 3;        // staging: pair, quarter-row
  const int cA = (pidx >> 2) & 7;
  const int fo_blk = t & 15, pb = t >> 4;    // gemm mapping
  const int fo0 = fo_blk * 8, p0 = pb * 4;
  const int cW = fo_blk & 7;
  const int cAg = pb & 7;
  const float4 c1a = *(const float4*)(ws + OFF_C1 + fo0);
  const float4 c1b = *(const float4*)(ws + OFF_C1 + fo0 + 4);
  const float c1v[8] = {c1a.x, c1a.y, c1a.z, c1a.w, c1b.x, c1b.y, c1b.z, c1b.w};

  for (int it = 0; it < 4; ++it) {
    const int chunk = blockIdx.x * 4 + it;
    __syncthreads();
    {  // stage A = h1 = relu(y_m - y_n + c0)
      const int gp = chunk * 128 + pidx;
      const int mg = idxg[gp];
      const float* __restrict__ ym = y + (long)mg * 128;
      const float* __restrict__ yn = y + (long)(gp >> 3) * 128;
      const float* __restrict__ c0p = ws + OFF_C0;
#pragma unroll
      for (int j = 0; j < 8; ++j) {
        const int k4 = s * 8 + j;
        const float4 a = *(const float4*)(ym + k4 * 4);
        const float4 bq = *(const float4*)(yn + k4 * 4);
        const float4 cc = *(const float4*)(c0p + k4 * 4);
        float4 h;
        h.x = relu_f(a.x - bq.x + cc.x);
        h.y = relu_f(a.y - bq.y + cc.y);
        h.z = relu_f(a.z - bq.z + cc.z);
        h.w = relu_f(a.w - bq.w + cc.w);
        A4[pidx * 32 + (k4 ^ cA)] = h;
      }
    }
    __syncthreads();

    float acc[4][8];
#pragma unroll
    for (int i = 0; i < 4; ++i)
#pragma unroll
      for (int j = 0; j < 8; ++j) acc[i][j] = 0.0f;

#pragma unroll 4
    for (int k4 = 0; k4 < 32; ++k4) {
      const int ka = k4 ^ cAg;
      const int kw = k4 ^ cW;
      float4 af[4];
#pragma unroll
      for (int i = 0; i < 4; ++i) af[i] = A4[(p0 + i) * 32 + ka];
      float4 wf[8];
#pragma unroll
      for (int j = 0; j < 8; ++j) wf[j] = W4[(fo0 + j) * 32 + kw];
#pragma unroll
      for (int i = 0; i < 4; ++i)
#pragma unroll
        for (int j = 0; j < 8; ++j) {
          acc[i][j] = fmaf(af[i].x, wf[j].x, acc[i][j]);
          acc[i][j] = fmaf(af[i].y, wf[j].y, acc[i][j]);
          acc[i][j] = fmaf(af[i].z, wf[j].z, acc[i][j]);
          acc[i][j] = fmaf(af[i].w, wf[j].w, acc[i][j]);
        }
    }

#pragma unroll
    for (int i = 0; i < 4; ++i) {
      const int gp = chunk * 128 + p0 + i;
      float4 o1, o2;
      o1.x = relu_f(acc[i][0] + c1v[0]);
      o1.y = relu_f(acc[i][1] + c1v[1]);
      o1.z = relu_f(acc[i][2] + c1v[2]);
      o1.w = relu_f(acc[i][3] + c1v[3]);
      o2.x = relu_f(acc[i][4] + c1v[4]);
      o2.y = relu_f(acc[i][5] + c1v[5]);
      o2.z = relu_f(acc[i][6] + c1v[6]);
      o2.w = relu_f(acc[i][7] + c1v[7]);
      *(float4*)(h2 + (long)gp * 128 + fo0) = o1;
      *(float4*)(h2 + (long)gp * 128 + fo0 + 4) = o2;
    }
  }
}

// ------------------------------- gemm2 -------------------------------------
__global__ __launch_bounds__(512, 2) void gemm2_kernel(float* __restrict__ ws,
                                                       float* __restrict__ out) {
  extern __shared__ float lds[];
  float4* __restrict__ W4 = (float4*)lds;
  float4* __restrict__ A4 = ((float4*)lds) + 4096;
  const float* __restrict__ h2 = ws + OFF_H2;
  const int t = threadIdx.x;

  {
    const float4* __restrict__ Wsrc = (const float4*)(ws + OFF_W2F);
#pragma unroll
    for (int j = 0; j < 8; ++j) {
      const int i4 = t + j * 512;
      const int fo = i4 >> 5, k4 = i4 & 31;
      W4[fo * 32 + (k4 ^ ((fo >> 3) & 7))] = Wsrc[i4];
    }
  }

  const int pidx = t >> 2, s = t & 3;
  const int cA = (pidx >> 2) & 7;
  const int fo_blk = t & 15, pb = t >> 4;
  const int fo0 = fo_blk * 8, p0 = pb * 4;
  const int cW = fo_blk & 7;
  const int cAg = pb & 7;
  const float4 c2a = *(const float4*)(ws + OFF_C2 + fo0);
  const float4 c2b = *(const float4*)(ws + OFF_C2 + fo0 + 4);
  const float c2v[8] = {c2a.x, c2a.y, c2a.z, c2a.w, c2b.x, c2b.y, c2b.z, c2b.w};

  for (int it = 0; it < 4; ++it) {
    const int chunk = blockIdx.x * 4 + it;
    __syncthreads();
    {  // stage A = h2 rows (already relu'd)
      const float4* __restrict__ src =
          (const float4*)h2 + (long)(chunk * 128 + pidx) * 32;
#pragma unroll
      for (int j = 0; j < 8; ++j) {
        const int k4 = s * 8 + j;
        A4[pidx * 32 + (k4 ^ cA)] = src[k4];
      }
    }
    __syncthreads();

    float acc[4][8];
#pragma unroll
    for (int i = 0; i < 4; ++i)
#pragma unroll
      for (int j = 0; j < 8; ++j) acc[i][j] = 0.0f;

#pragma unroll 4
    for (int k4 = 0; k4 < 32; ++k4) {
      const int ka = k4 ^ cAg;
      const int kw = k4 ^ cW;
      float4 af[4];
#pragma unroll
      for (int i = 0; i < 4; ++i) af[i] = A4[(p0 + i) * 32 + ka];
      float4 wf[8];
#pragma unroll
      for (int j = 0; j < 8; ++j) wf[j] = W4[(fo0 + j) * 32 + kw];
#pragma unroll
      for (int i = 0; i < 4; ++i)
#pragma unroll
        for (int j = 0; j < 8; ++j) {
          acc[i][j] = fmaf(af[i].x, wf[j].x, acc[i][j]);
          acc[i][j] = fmaf(af[i].y, wf[j].y, acc[i][j]);
          acc[i][j] = fmaf(af[i].z, wf[j].z, acc[i][j]);
          acc[i][j] = fmaf(af[i].w, wf[j].w, acc[i][j]);
        }
    }

    // epilogue: relu(acc + c2), max over this thread's 4 pairs, then partner
    float mx[8];
#pragma unroll
    for (int j = 0; j < 8; ++j) {
      const float v0 = relu_f(acc[0][j] + c2v[j]);
      const float v1 = relu_f(acc[1][j] + c2v[j]);
      const float v2 = relu_f(acc[2][j] + c2v[j]);
      const float v3 = relu_f(acc[3][j] + c2v[j]);
      mx[j] = fmaxf(fmaxf(v0, v1), fmaxf(v2, v3));
    }
#pragma unroll
    for (int j = 0; j < 8; ++j)
      mx[j] = fmaxf(mx[j], __shfl_xor(mx[j], 16, 64));

    __syncthreads();  // all A4 reads done before reuse as transpose buffer
    float* __restrict__ ldso = lds + 16384;  // 16 queries x 128 feats
    if ((pb & 1) == 0) {
      const int qi = pb >> 1;
#pragma unroll
      for (int j = 0; j < 8; ++j) ldso[qi * 128 + fo0 + j] = mx[j];
    }
    __syncthreads();
    {
      const int f = t >> 2, qg = t & 3;
      const int qbase = chunk * 16;
      const int b = qbase >> 11, n0 = qbase & 2047;
      float4 o;
      o.x = ldso[(qg * 4 + 0) * 128 + f];
      o.y = ldso[(qg * 4 + 1) * 128 + f];
      o.z = ldso[(qg * 4 + 2) * 128 + f];
      o.w = ldso[(qg * 4 + 3) * 128 + f];
      *(float4*)(out + (long)(b * 128 + f) * 2048 + n0 + qg * 4) = o;
    }
  }
}

// ------------------------------- launch ------------------------------------
extern "C" void kernel_launch(void* const* d_in, const int* in_sizes, int n_in,
                              void* d_out, int out_size, void* d_ws,
                              size_t ws_size, hipStream_t stream) {
  (void)in_sizes; (void)n_in; (void)out_size; (void)ws_size;
  const float* x   = (const float*)d_in[0];
  const float* w0  = (const float*)d_in[1];
  const float* b0  = (const float*)d_in[2];
  const float* wst = (const float*)d_in[3];
  const float* bst = (const float*)d_in[4];
  const float* g   = (const float*)d_in[5];
  const float* be  = (const float*)d_in[6];
  const float* bm  = (const float*)d_in[7];
  const float* bv  = (const float*)d_in[8];
  float* out = (float*)d_out;
  float* ws  = (float*)d_ws;

  hipFuncSetAttribute((const void*)gemm1_kernel,
                      hipFuncAttributeMaxDynamicSharedMemorySize, 131072);
  hipFuncSetAttribute((const void*)gemm2_kernel,
                      hipFuncAttributeMaxDynamicSharedMemorySize, 131072);

  prep_kernel<<<1, 256, 0, stream>>>(w0, b0, wst, bst, g, be, bm, bv, ws);
  y_kernel<<<NQ * DIMF / 256, 256, 0, stream>>>(x, ws);
  knn_part_kernel<<<256, 256, 0, stream>>>(x, ws);
  knn_merge_kernel<<<NQ / 256, 256, 0, stream>>>(ws);
  gemm1_kernel<<<256, 512, 131072, stream>>>(ws);
  gemm2_kernel<<<256, 512, 131072, stream>>>(ws, out);
}

// Round 2
// 173.939 us; speedup vs baseline: 1.9942x; 1.9942x over previous
//
#include <hip/hip_runtime.h>

// ---------------------------------------------------------------------------
// FeatureNet: kNN(K=8) relative grouping -> [conv1x1+BN+ReLU] x3 -> max over K
// B=8, N=2048, DIM=128, fp32 in/out.
//
// prep     : fold BN into weights/biases
// y        : y[q][f] = W0f . x[q]
// knn_part : 16 ranges x 128 candidates, branchless top-8, 1024 WGs
// knn_merge: merge 16 partial top-8 lists -> idx[q][8]
// gemm1    : h2 = relu(W1f . relu(y_m - y_n + c0) + c1)   [bf16x3 MFMA]
// gemm2    : h3 = relu(W2f . h2 + c2); out = max over K   [bf16x3 MFMA]
// ---------------------------------------------------------------------------

#define EPSF 1e-5f
#define FMAXV 3.402823466e+38f

#define NB 8
#define NN 2048
#define KNBR 8
#define DIMF 128
#define NQ (NB * NN)        // 16384
#define NPAIR (NQ * KNBR)   // 131072

// ws layout (float offsets)
#define OFF_W1F 0
#define OFF_W2F 16384
#define OFF_C0 32768
#define OFF_C1 32896
#define OFF_C2 33024
#define OFF_W0F 33152                    // 384
#define OFF_Y 33792                      // 2097152 floats
#define OFF_IDX (OFF_Y + NQ * DIMF)      // 131072 ints
#define OFF_H2P (OFF_IDX + NPAIR)        // 16777216 u32
// knn partial lists (4.19M floats) ALIAS the H2P region (used before gemm1).

typedef __attribute__((ext_vector_type(4))) float f32x4;
typedef __attribute__((ext_vector_type(8))) short short8v;

__device__ __forceinline__ float relu_f(float a) { return fmaxf(a, 0.0f); }

// fp32 -> bf16(hi, RNE) + bf16(lo, trunc of residual)
__device__ __forceinline__ void split3(float f, unsigned& hi, unsigned& lo) {
  const unsigned u = __float_as_uint(f);
  const unsigned h = (u + 0x7FFFu + ((u >> 16) & 1u)) >> 16;
  const float hf = __uint_as_float(h << 16);
  lo = __float_as_uint(f - hf) >> 16;
  hi = h;
}

// ------------------------------- prep --------------------------------------
__global__ __launch_bounds__(256) void prep_kernel(
    const float* __restrict__ w0, const float* __restrict__ b0,
    const float* __restrict__ wstk, const float* __restrict__ bstk,
    const float* __restrict__ g, const float* __restrict__ be,
    const float* __restrict__ bm, const float* __restrict__ bv,
    float* __restrict__ ws) {
  const int t = threadIdx.x;
  for (int i = t; i < 16384; i += 256) {
    const int fo = i >> 7;
    const float s1 = g[128 + fo] / sqrtf(bv[128 + fo] + EPSF);
    const float s2 = g[256 + fo] / sqrtf(bv[256 + fo] + EPSF);
    ws[OFF_W1F + i] = wstk[i] * s1;
    ws[OFF_W2F + i] = wstk[16384 + i] * s2;
  }
  if (t < 128) {
    const int fo = t;
    const float s0 = g[fo] / sqrtf(bv[fo] + EPSF);
    const float s1 = g[128 + fo] / sqrtf(bv[128 + fo] + EPSF);
    const float s2 = g[256 + fo] / sqrtf(bv[256 + fo] + EPSF);
    ws[OFF_C0 + fo] = (b0[fo] - bm[fo]) * s0 + be[fo];
    ws[OFF_C1 + fo] = (bstk[fo] - bm[128 + fo]) * s1 + be[128 + fo];
    ws[OFF_C2 + fo] = (bstk[128 + fo] - bm[256 + fo]) * s2 + be[256 + fo];
    ws[OFF_W0F + 3 * fo + 0] = w0[3 * fo + 0] * s0;
    ws[OFF_W0F + 3 * fo + 1] = w0[3 * fo + 1] * s0;
    ws[OFF_W0F + 3 * fo + 2] = w0[3 * fo + 2] * s0;
  }
}

// ------------------------------- ycomp -------------------------------------
__global__ __launch_bounds__(256) void y_kernel(const float* __restrict__ x,
                                                float* __restrict__ ws) {
  const int gid = blockIdx.x * 256 + threadIdx.x;  // 2,097,152
  const int q = gid >> 7, f = gid & 127;
  const int b = q >> 11, n = q & 2047;
  const float* __restrict__ W0f = ws + OFF_W0F;
  const float w0 = W0f[f * 3 + 0], w1 = W0f[f * 3 + 1], w2 = W0f[f * 3 + 2];
  const float x0 = x[b * 6144 + n];
  const float x1 = x[b * 6144 + 2048 + n];
  const float x2 = x[b * 6144 + 4096 + n];
  ws[OFF_Y + gid] = fmaf(w2, x2, fmaf(w1, x1, w0 * x0));
}

// ------------------------------- knn ---------------------------------------
#define KNN_CSWAP(da, db, ia, ib)            \
  {                                          \
    const bool c_ = (db) < (da);             \
    const float lo_ = c_ ? (db) : (da);      \
    const float hi_ = c_ ? (da) : (db);      \
    const int il_ = c_ ? (ib) : (ia);        \
    const int ih_ = c_ ? (ia) : (ib);        \
    (da) = lo_; (db) = hi_;                  \
    (ia) = il_; (ib) = ih_;                  \
  }

#define KNN_INSERT_BL(d, mi)                  \
  {                                           \
    const bool cc_ = (d) < b7v;               \
    b7v = cc_ ? (d) : b7v;                    \
    i7v = cc_ ? (mi) : i7v;                   \
    KNN_CSWAP(b6v, b7v, i6v, i7v)             \
    KNN_CSWAP(b5v, b6v, i5v, i6v)             \
    KNN_CSWAP(b4v, b5v, i4v, i5v)             \
    KNN_CSWAP(b3v, b4v, i3v, i4v)             \
    KNN_CSWAP(b2v, b3v, i2v, i3v)             \
    KNN_CSWAP(b1v, b2v, i1v, i2v)             \
    KNN_CSWAP(b0v, b1v, i0v, i1v)             \
  }

// wg = qb*16 + r ; 256 threads = 256 queries; 128 candidates (range r)
__global__ __launch_bounds__(256) void knn_part_kernel(
    const float* __restrict__ x, float* __restrict__ ws) {
  __shared__ float4 xs4[128];
  const int t = threadIdx.x;
  const int wg = blockIdx.x;  // 1024
  const int qb = wg >> 4, r = wg & 15;
  const int b = qb >> 3;
  const float* __restrict__ xb = x + b * 3 * NN;
  if (t < 128) {
    const int i = r * 128 + t;
    const float a0 = xb[i];
    const float a1 = xb[2048 + i];
    const float a2 = xb[4096 + i];
    const float sq = fmaf(a2, a2, fmaf(a1, a1, a0 * a0));
    xs4[t] = make_float4(a0, a1, a2, sq);
  }
  __syncthreads();
  const int n = (qb & 7) * 256 + t;
  const int q = b * NN + n;
  const float qx0 = xb[n], qx1 = xb[2048 + n], qx2 = xb[4096 + n];
  const float sqn = fmaf(qx2, qx2, fmaf(qx1, qx1, qx0 * qx0));
  float b0v = FMAXV, b1v = FMAXV, b2v = FMAXV, b3v = FMAXV,
        b4v = FMAXV, b5v = FMAXV, b6v = FMAXV, b7v = FMAXV;
  int i0v = 0, i1v = 0, i2v = 0, i3v = 0, i4v = 0, i5v = 0, i6v = 0, i7v = 0;
  const int gbase = b * NN + r * 128;
#pragma unroll 4
  for (int mm = 0; mm < 128; ++mm) {
    const float4 c = xs4[mm];
    const float inner = fmaf(qx2, c.z, fmaf(qx1, c.y, qx0 * c.x));
    const float d = (sqn - 2.0f * inner) + c.w;
    const int mi = gbase + mm;
    KNN_INSERT_BL(d, mi)
  }
  float2* __restrict__ part = (float2*)(ws + OFF_H2P);
  const int eb = r * 8;
  part[(eb + 0) * NQ + q] = make_float2(b0v, __int_as_float(i0v));
  part[(eb + 1) * NQ + q] = make_float2(b1v, __int_as_float(i1v));
  part[(eb + 2) * NQ + q] = make_float2(b2v, __int_as_float(i2v));
  part[(eb + 3) * NQ + q] = make_float2(b3v, __int_as_float(i3v));
  part[(eb + 4) * NQ + q] = make_float2(b4v, __int_as_float(i4v));
  part[(eb + 5) * NQ + q] = make_float2(b5v, __int_as_float(i5v));
  part[(eb + 6) * NQ + q] = make_float2(b6v, __int_as_float(i6v));
  part[(eb + 7) * NQ + q] = make_float2(b7v, __int_as_float(i7v));
}

__global__ __launch_bounds__(256) void knn_merge_kernel(float* __restrict__ ws) {
  const int q = blockIdx.x * 256 + threadIdx.x;  // 16384
  const float2* __restrict__ part = (const float2*)(ws + OFF_H2P);
  float b0v = FMAXV, b1v = FMAXV, b2v = FMAXV, b3v = FMAXV,
        b4v = FMAXV, b5v = FMAXV, b6v = FMAXV, b7v = FMAXV;
  int i0v = 0, i1v = 0, i2v = 0, i3v = 0, i4v = 0, i5v = 0, i6v = 0, i7v = 0;
#pragma unroll 4
  for (int e = 0; e < 128; ++e) {
    const float2 en = part[(long)e * NQ + q];
    const float d = en.x;
    const int mi = __float_as_int(en.y);
    KNN_INSERT_BL(d, mi)
  }
  int* __restrict__ idxg = (int*)(ws + OFF_IDX);
  int* o = idxg + q * 8;
  o[0] = i0v; o[1] = i1v; o[2] = i2v; o[3] = i3v;
  o[4] = i4v; o[5] = i5v; o[6] = i6v; o[7] = i7v;
}

// --------------------------- gemm helpers ----------------------------------
// LDS (64KB dynamic): Ahi plane [128 rows][16 x 16B chunks] at 0,
//                     Alo plane at +32768. 16B chunk col swizzled: col = kc ^ (row&7).
// Epilogue aliases the whole 64KB as a u32/float plane.
__device__ __forceinline__ f32x4 mfma16x16x32bf(short8v a, short8v b, f32x4 c) {
  return __builtin_amdgcn_mfma_f32_16x16x32_bf16(a, b, c, 0, 0, 0);
}

__device__ __forceinline__ void pack8(const float* v, int4& hp, int4& lp) {
  unsigned hh[8], ll[8];
#pragma unroll
  for (int e = 0; e < 8; ++e) split3(v[e], hh[e], ll[e]);
  hp.x = (int)(hh[0] | (hh[1] << 16));
  hp.y = (int)(hh[2] | (hh[3] << 16));
  hp.z = (int)(hh[4] | (hh[5] << 16));
  hp.w = (int)(hh[6] | (hh[7] << 16));
  lp.x = (int)(ll[0] | (ll[1] << 16));
  lp.y = (int)(ll[2] | (ll[3] << 16));
  lp.z = (int)(ll[4] | (ll[5] << 16));
  lp.w = (int)(ll[6] | (ll[7] << 16));
}

// ------------------------------- gemm1 -------------------------------------
__global__ __launch_bounds__(512, 4) void gemm1_kernel(float* __restrict__ ws) {
  extern __shared__ char lds[];
  const float* __restrict__ y = ws + OFF_Y;
  const int* __restrict__ idxg = (const int*)(ws + OFF_IDX);
  unsigned* __restrict__ h2p = (unsigned*)(ws + OFF_H2P);
  const int t = threadIdx.x;
  const int lane = t & 63, w = t >> 6;
  const int wr = w >> 2, wc = w & 3;  // wave tile: 64 pairs x 32 fo

  // W1f fragments -> registers: [ftile][kstep][hi/lo]
  short8v wf[2][4][2];
  {
    const float* __restrict__ W = ws + OFF_W1F;
#pragma unroll
    for (int ft = 0; ft < 2; ++ft) {
      const int fo = wc * 32 + ft * 16 + (lane & 15);
#pragma unroll
      for (int ks = 0; ks < 4; ++ks) {
        const int kb = ks * 32 + (lane >> 4) * 8;
        const float4 wa = *(const float4*)(W + fo * 128 + kb);
        const float4 wb = *(const float4*)(W + fo * 128 + kb + 4);
        const float v[8] = {wa.x, wa.y, wa.z, wa.w, wb.x, wb.y, wb.z, wb.w};
        short8v h8, l8;
#pragma unroll
        for (int e = 0; e < 8; ++e) {
          unsigned hh, ll;
          split3(v[e], hh, ll);
          h8[e] = (short)hh;
          l8[e] = (short)ll;
        }
        wf[ft][ks][0] = h8;
        wf[ft][ks][1] = l8;
      }
    }
  }
  const float c1v0 = (ws + OFF_C1)[wc * 32 + (lane & 15)];
  const float c1v1 = (ws + OFF_C1)[wc * 32 + 16 + (lane & 15)];

  const int pidx = t >> 2, s = t & 3;

  for (int it = 0; it < 2; ++it) {
    const int chunk = blockIdx.x * 2 + it;
    if (it) __syncthreads();
    {  // stage A = h1 = relu(y_m - y_n + c0), split to bf16 hi/lo planes
      const int gp = chunk * 128 + pidx;
      const int mg = idxg[gp];
      const float* __restrict__ ym = y + (long)mg * 128 + s * 32;
      const float* __restrict__ yn = y + (long)(gp >> 3) * 128 + s * 32;
      const float* __restrict__ c0 = ws + OFF_C0 + s * 32;
#pragma unroll
      for (int cj = 0; cj < 4; ++cj) {
        const float4 a0 = *(const float4*)(ym + cj * 8);
        const float4 a1 = *(const float4*)(ym + cj * 8 + 4);
        const float4 n0 = *(const float4*)(yn + cj * 8);
        const float4 n1 = *(const float4*)(yn + cj * 8 + 4);
        const float4 ca = *(const float4*)(c0 + cj * 8);
        const float4 cb = *(const float4*)(c0 + cj * 8 + 4);
        const float hv[8] = {
            relu_f(a0.x - n0.x + ca.x), relu_f(a0.y - n0.y + ca.y),
            relu_f(a0.z - n0.z + ca.z), relu_f(a0.w - n0.w + ca.w),
            relu_f(a1.x - n1.x + cb.x), relu_f(a1.y - n1.y + cb.y),
            relu_f(a1.z - n1.z + cb.z), relu_f(a1.w - n1.w + cb.w)};
        int4 hp, lp;
        pack8(hv, hp, lp);
        const int kc = s * 4 + cj;
        const int col = kc ^ (pidx & 7);
        *(int4*)(lds + pidx * 256 + col * 16) = hp;
        *(int4*)(lds + 32768 + pidx * 256 + col * 16) = lp;
      }
    }
    __syncthreads();

    f32x4 acc[4][2];
#pragma unroll
    for (int pt = 0; pt < 4; ++pt)
#pragma unroll
      for (int ft = 0; ft < 2; ++ft) acc[pt][ft] = (f32x4){0.f, 0.f, 0.f, 0.f};

#pragma unroll
    for (int ks = 0; ks < 4; ++ks) {
#pragma unroll
      for (int pt = 0; pt < 4; ++pt) {
        const int row = wr * 64 + pt * 16 + (lane & 15);
        const int kc = ks * 4 + (lane >> 4);
        const int col = kc ^ (row & 7);
        const short8v ah = *(const short8v*)(lds + row * 256 + col * 16);
        const short8v al = *(const short8v*)(lds + 32768 + row * 256 + col * 16);
#pragma unroll
        for (int ft = 0; ft < 2; ++ft) {
          acc[pt][ft] = mfma16x16x32bf(ah, wf[ft][ks][0], acc[pt][ft]);
          acc[pt][ft] = mfma16x16x32bf(ah, wf[ft][ks][1], acc[pt][ft]);
          acc[pt][ft] = mfma16x16x32bf(al, wf[ft][ks][0], acc[pt][ft]);
        }
      }
    }
    __syncthreads();
    {  // epilogue: relu(acc+c1) -> packed bf16x2 u32 into LDS plane
      unsigned* __restrict__ H = (unsigned*)lds;
#pragma unroll
      for (int pt = 0; pt < 4; ++pt)
#pragma unroll
        for (int ft = 0; ft < 2; ++ft) {
          const int fo = wc * 32 + ft * 16 + (lane & 15);
          const float cb = ft ? c1v1 : c1v0;
#pragma unroll
          for (int reg = 0; reg < 4; ++reg) {
            const int p = wr * 64 + pt * 16 + (lane >> 4) * 4 + reg;
            const float vv = relu_f(acc[pt][ft][reg] + cb);
            unsigned hh, ll;
            split3(vv, hh, ll);
            H[p * 128 + fo] = (hh << 16) | ll;
          }
        }
    }
    __syncthreads();
    {  // coalesced copy LDS -> h2p
      const int4* __restrict__ Hs = (const int4*)lds;
      int4* __restrict__ dst = (int4*)(h2p + (long)chunk * 16384);
#pragma unroll
      for (int j = 0; j < 8; ++j) dst[t + j * 512] = Hs[t + j * 512];
    }
  }
}

// ------------------------------- gemm2 -------------------------------------
__global__ __launch_bounds__(512, 4) void gemm2_kernel(float* __restrict__ ws,
                                                       float* __restrict__ out) {
  extern __shared__ char lds[];
  const unsigned* __restrict__ h2p = (const unsigned*)(ws + OFF_H2P);
  const int t = threadIdx.x;
  const int lane = t & 63, w = t >> 6;
  const int wr = w >> 2, wc = w & 3;

  short8v wf[2][4][2];
  {
    const float* __restrict__ W = ws + OFF_W2F;
#pragma unroll
    for (int ft = 0; ft < 2; ++ft) {
      const int fo = wc * 32 + ft * 16 + (lane & 15);
#pragma unroll
      for (int ks = 0; ks < 4; ++ks) {
        const int kb = ks * 32 + (lane >> 4) * 8;
        const float4 wa = *(const float4*)(W + fo * 128 + kb);
        const float4 wb = *(const float4*)(W + fo * 128 + kb + 4);
        const float v[8] = {wa.x, wa.y, wa.z, wa.w, wb.x, wb.y, wb.z, wb.w};
        short8v h8, l8;
#pragma unroll
        for (int e = 0; e < 8; ++e) {
          unsigned hh, ll;
          split3(v[e], hh, ll);
          h8[e] = (short)hh;
          l8[e] = (short)ll;
        }
        wf[ft][ks][0] = h8;
        wf[ft][ks][1] = l8;
      }
    }
  }
  const float c2v0 = (ws + OFF_C2)[wc * 32 + (lane & 15)];
  const float c2v1 = (ws + OFF_C2)[wc * 32 + 16 + (lane & 15)];

  const int pidx = t >> 2, s = t & 3;

  for (int it = 0; it < 2; ++it) {
    const int chunk = blockIdx.x * 2 + it;
    if (it) __syncthreads();
    {  // stage A from packed h2p
      const unsigned* __restrict__ src =
          h2p + (long)(chunk * 128 + pidx) * 128 + s * 32;
#pragma unroll
      for (int cj = 0; cj < 4; ++cj) {
        const int4 u0 = *(const int4*)(src + cj * 8);
        const int4 u1 = *(const int4*)(src + cj * 8 + 4);
        const unsigned a0 = (unsigned)u0.x, a1 = (unsigned)u0.y,
                       a2 = (unsigned)u0.z, a3 = (unsigned)u0.w;
        const unsigned b0 = (unsigned)u1.x, b1 = (unsigned)u1.y,
                       b2 = (unsigned)u1.z, b3 = (unsigned)u1.w;
        int4 hp, lp;
        hp.x = (int)((a0 >> 16) | (a1 & 0xFFFF0000u));
        hp.y = (int)((a2 >> 16) | (a3 & 0xFFFF0000u));
        hp.z = (int)((b0 >> 16) | (b1 & 0xFFFF0000u));
        hp.w = (int)((b2 >> 16) | (b3 & 0xFFFF0000u));
        lp.x = (int)((a0 & 0xFFFFu) | (a1 << 16));
        lp.y = (int)((a2 & 0xFFFFu) | (a3 << 16));
        lp.z = (int)((b0 & 0xFFFFu) | (b1 << 16));
        lp.w = (int)((b2 & 0xFFFFu) | (b3 << 16));
        const int kc = s * 4 + cj;
        const int col = kc ^ (pidx & 7);
        *(int4*)(lds + pidx * 256 + col * 16) = hp;
        *(int4*)(lds + 32768 + pidx * 256 + col * 16) = lp;
      }
    }
    __syncthreads();

    f32x4 acc[4][2];
#pragma unroll
    for (int pt = 0; pt < 4; ++pt)
#pragma unroll
      for (int ft = 0; ft < 2; ++ft) acc[pt][ft] = (f32x4){0.f, 0.f, 0.f, 0.f};

#pragma unroll
    for (int ks = 0; ks < 4; ++ks) {
#pragma unroll
      for (int pt = 0; pt < 4; ++pt) {
        const int row = wr * 64 + pt * 16 + (lane & 15);
        const int kc = ks * 4 + (lane >> 4);
        const int col = kc ^ (row & 7);
        const short8v ah = *(const short8v*)(lds + row * 256 + col * 16);
        const short8v al = *(const short8v*)(lds + 32768 + row * 256 + col * 16);
#pragma unroll
        for (int ft = 0; ft < 2; ++ft) {
          acc[pt][ft] = mfma16x16x32bf(ah, wf[ft][ks][0], acc[pt][ft]);
          acc[pt][ft] = mfma16x16x32bf(ah, wf[ft][ks][1], acc[pt][ft]);
          acc[pt][ft] = mfma16x16x32bf(al, wf[ft][ks][0], acc[pt][ft]);
        }
      }
    }
    __syncthreads();
    {  // epilogue: relu(acc+c2), max over 8 pairs/query -> LDSO[16][128]
      float* __restrict__ LDSO = (float*)lds;
      const int g = lane >> 4;
#pragma unroll
      for (int pt = 0; pt < 4; ++pt)
#pragma unroll
        for (int ft = 0; ft < 2; ++ft) {
          const int fo = wc * 32 + ft * 16 + (lane & 15);
          const float cb = ft ? c2v1 : c2v0;
          const float v0 = relu_f(acc[pt][ft][0] + cb);
          const float v1 = relu_f(acc[pt][ft][1] + cb);
          const float v2 = relu_f(acc[pt][ft][2] + cb);
          const float v3 = relu_f(acc[pt][ft][3] + cb);
          float m = fmaxf(fmaxf(v0, v1), fmaxf(v2, v3));
          m = fmaxf(m, __shfl_xor(m, 16, 64));
          if ((g & 1) == 0) {
            const int qloc = wr * 8 + pt * 2 + (g >> 1);
            LDSO[qloc * 128 + fo] = m;
          }
        }
    }
    __syncthreads();
    {  // coalesced transpose-out: out[b][f][n]
      const float* __restrict__ LDSO = (const float*)lds;
      const int f = t >> 2, qg = t & 3;
      const int qbase = chunk * 16;
      const int b = qbase >> 11, n0 = qbase & 2047;
      float4 o;
      o.x = LDSO[(qg * 4 + 0) * 128 + f];
      o.y = LDSO[(qg * 4 + 1) * 128 + f];
      o.z = LDSO[(qg * 4 + 2) * 128 + f];
      o.w = LDSO[(qg * 4 + 3) * 128 + f];
      *(float4*)(out + (long)(b * 128 + f) * 2048 + n0 + qg * 4) = o;
    }
  }
}

// ------------------------------- launch ------------------------------------
extern "C" void kernel_launch(void* const* d_in, const int* in_sizes, int n_in,
                              void* d_out, int out_size, void* d_ws,
                              size_t ws_size, hipStream_t stream) {
  (void)in_sizes; (void)n_in; (void)out_size; (void)ws_size;
  const float* x = (const float*)d_in[0];
  const float* w0 = (const float*)d_in[1];
  const float* b0 = (const float*)d_in[2];
  const float* wst = (const float*)d_in[3];
  const float* bst = (const float*)d_in[4];
  const float* g = (const float*)d_in[5];
  const float* be = (const float*)d_in[6];
  const float* bm = (const float*)d_in[7];
  const float* bv = (const float*)d_in[8];
  float* out = (float*)d_out;
  float* ws = (float*)d_ws;

  hipFuncSetAttribute((const void*)gemm1_kernel,
                      hipFuncAttributeMaxDynamicSharedMemorySize, 65536);
  hipFuncSetAttribute((const void*)gemm2_kernel,
                      hipFuncAttributeMaxDynamicSharedMemorySize, 65536);

  prep_kernel<<<1, 256, 0, stream>>>(w0, b0, wst, bst, g, be, bm, bv, ws);
  y_kernel<<<NQ * DIMF / 256, 256, 0, stream>>>(x, ws);
  knn_part_kernel<<<1024, 256, 0, stream>>>(x, ws);
  knn_merge_kernel<<<NQ / 256, 256, 0, stream>>>(ws);
  gemm1_kernel<<<512, 512, 65536, stream>>>(ws);
  gemm2_kernel<<<512, 512, 65536, stream>>>(ws, out);
}

// Round 3
// 171.393 us; speedup vs baseline: 2.0239x; 1.0149x over previous
//
#include <hip/hip_runtime.h>

// ---------------------------------------------------------------------------
// FeatureNet: kNN(K=8) relative grouping -> [conv1x1+BN+ReLU] x3 -> max over K
// B=8, N=2048, DIM=128, fp32 in/out.
//
// prep     : fold BN into weights/biases; W1/W2 packed u32 (bf16 hi<<16 | lo)
// y        : y[q][f] = W0f . x[q]
// knn_part : 16 ranges x 128 candidates, branchless top-8, 1024 WGs
// knn_merge: merge 16 partial top-8 lists -> idx[q][8]
// fused    : per chunk of 64 pairs: h1 -> g1 MFMA -> H(LDS) -> g2 MFMA -> max
//            XCD-aligned chunk mapping so each XCD's y-gather is one batch
//            (1 MB, L2-resident). W streamed from L1 each k-step (low VGPR).
// ---------------------------------------------------------------------------

#define EPSF 1e-5f
#define FMAXV 3.402823466e+38f

#define NB 8
#define NN 2048
#define KNBR 8
#define DIMF 128
#define NQ (NB * NN)        // 16384
#define NPAIR (NQ * KNBR)   // 131072

// ws layout (float offsets)
#define OFF_W1F 0                        // 16384 u32 (packed bf16 hi|lo)
#define OFF_W2F 16384                    // 16384 u32
#define OFF_C0 32768
#define OFF_C1 32896
#define OFF_C2 33024
#define OFF_W0F 33152                    // 384
#define OFF_Y 33792                      // 2097152 floats
#define OFF_IDX (OFF_Y + NQ * DIMF)      // 131072 ints
#define OFF_PART (OFF_IDX + NPAIR)       // knn partials: 16384*128*2 floats

typedef __attribute__((ext_vector_type(4))) float f32x4;
typedef __attribute__((ext_vector_type(8))) short short8v;

__device__ __forceinline__ float relu_f(float a) { return fmaxf(a, 0.0f); }

// fp32 -> bf16(hi, RNE) + bf16(lo, trunc of residual)
__device__ __forceinline__ void split3(float f, unsigned& hi, unsigned& lo) {
  const unsigned u = __float_as_uint(f);
  const unsigned h = (u + 0x7FFFu + ((u >> 16) & 1u)) >> 16;
  const float hf = __uint_as_float(h << 16);
  lo = __float_as_uint(f - hf) >> 16;
  hi = h;
}

__device__ __forceinline__ f32x4 mfma16x16x32bf(short8v a, short8v b, f32x4 c) {
  return __builtin_amdgcn_mfma_f32_16x16x32_bf16(a, b, c, 0, 0, 0);
}

// ------------------------------- prep --------------------------------------
__global__ __launch_bounds__(256) void prep_kernel(
    const float* __restrict__ w0, const float* __restrict__ b0,
    const float* __restrict__ wstk, const float* __restrict__ bstk,
    const float* __restrict__ g, const float* __restrict__ be,
    const float* __restrict__ bm, const float* __restrict__ bv,
    float* __restrict__ ws) {
  const int t = threadIdx.x;
  unsigned* __restrict__ wsu = (unsigned*)ws;
  for (int i = t; i < 16384; i += 256) {
    const int fo = i >> 7;
    const float s1 = g[128 + fo] / sqrtf(bv[128 + fo] + EPSF);
    const float s2 = g[256 + fo] / sqrtf(bv[256 + fo] + EPSF);
    unsigned h1, l1, h2, l2;
    split3(wstk[i] * s1, h1, l1);
    split3(wstk[16384 + i] * s2, h2, l2);
    wsu[OFF_W1F + i] = (h1 << 16) | l1;
    wsu[OFF_W2F + i] = (h2 << 16) | l2;
  }
  if (t < 128) {
    const int fo = t;
    const float s0 = g[fo] / sqrtf(bv[fo] + EPSF);
    const float s1 = g[128 + fo] / sqrtf(bv[128 + fo] + EPSF);
    const float s2 = g[256 + fo] / sqrtf(bv[256 + fo] + EPSF);
    ws[OFF_C0 + fo] = (b0[fo] - bm[fo]) * s0 + be[fo];
    ws[OFF_C1 + fo] = (bstk[fo] - bm[128 + fo]) * s1 + be[128 + fo];
    ws[OFF_C2 + fo] = (bstk[128 + fo] - bm[256 + fo]) * s2 + be[256 + fo];
    ws[OFF_W0F + 3 * fo + 0] = w0[3 * fo + 0] * s0;
    ws[OFF_W0F + 3 * fo + 1] = w0[3 * fo + 1] * s0;
    ws[OFF_W0F + 3 * fo + 2] = w0[3 * fo + 2] * s0;
  }
}

// ------------------------------- ycomp -------------------------------------
__global__ __launch_bounds__(256) void y_kernel(const float* __restrict__ x,
                                                float* __restrict__ ws) {
  const int gid = blockIdx.x * 256 + threadIdx.x;  // 2,097,152
  const int q = gid >> 7, f = gid & 127;
  const int b = q >> 11, n = q & 2047;
  const float* __restrict__ W0f = ws + OFF_W0F;
  const float w0 = W0f[f * 3 + 0], w1 = W0f[f * 3 + 1], w2 = W0f[f * 3 + 2];
  const float x0 = x[b * 6144 + n];
  const float x1 = x[b * 6144 + 2048 + n];
  const float x2 = x[b * 6144 + 4096 + n];
  ws[OFF_Y + gid] = fmaf(w2, x2, fmaf(w1, x1, w0 * x0));
}

// ------------------------------- knn ---------------------------------------
#define KNN_CSWAP(da, db, ia, ib)            \
  {                                          \
    const bool c_ = (db) < (da);             \
    const float lo_ = c_ ? (db) : (da);      \
    const float hi_ = c_ ? (da) : (db);      \
    const int il_ = c_ ? (ib) : (ia);        \
    const int ih_ = c_ ? (ia) : (ib);        \
    (da) = lo_; (db) = hi_;                  \
    (ia) = il_; (ib) = ih_;                  \
  }

#define KNN_INSERT_BL(d, mi)                  \
  {                                           \
    const bool cc_ = (d) < b7v;               \
    b7v = cc_ ? (d) : b7v;                    \
    i7v = cc_ ? (mi) : i7v;                   \
    KNN_CSWAP(b6v, b7v, i6v, i7v)             \
    KNN_CSWAP(b5v, b6v, i5v, i6v)             \
    KNN_CSWAP(b4v, b5v, i4v, i5v)             \
    KNN_CSWAP(b3v, b4v, i3v, i4v)             \
    KNN_CSWAP(b2v, b3v, i2v, i3v)             \
    KNN_CSWAP(b1v, b2v, i1v, i2v)             \
    KNN_CSWAP(b0v, b1v, i0v, i1v)             \
  }

// wg = qb*16 + r ; 256 threads = 256 queries; 128 candidates (range r)
__global__ __launch_bounds__(256) void knn_part_kernel(
    const float* __restrict__ x, float* __restrict__ ws) {
  __shared__ float4 xs4[128];
  const int t = threadIdx.x;
  const int wg = blockIdx.x;  // 1024
  const int qb = wg >> 4, r = wg & 15;
  const int b = qb >> 3;
  const float* __restrict__ xb = x + b * 3 * NN;
  if (t < 128) {
    const int i = r * 128 + t;
    const float a0 = xb[i];
    const float a1 = xb[2048 + i];
    const float a2 = xb[4096 + i];
    const float sq = fmaf(a2, a2, fmaf(a1, a1, a0 * a0));
    xs4[t] = make_float4(a0, a1, a2, sq);
  }
  __syncthreads();
  const int n = (qb & 7) * 256 + t;
  const int q = b * NN + n;
  const float qx0 = xb[n], qx1 = xb[2048 + n], qx2 = xb[4096 + n];
  const float sqn = fmaf(qx2, qx2, fmaf(qx1, qx1, qx0 * qx0));
  float b0v = FMAXV, b1v = FMAXV, b2v = FMAXV, b3v = FMAXV,
        b4v = FMAXV, b5v = FMAXV, b6v = FMAXV, b7v = FMAXV;
  int i0v = 0, i1v = 0, i2v = 0, i3v = 0, i4v = 0, i5v = 0, i6v = 0, i7v = 0;
  const int gbase = b * NN + r * 128;
#pragma unroll 4
  for (int mm = 0; mm < 128; ++mm) {
    const float4 c = xs4[mm];
    const float inner = fmaf(qx2, c.z, fmaf(qx1, c.y, qx0 * c.x));
    const float d = (sqn - 2.0f * inner) + c.w;
    const int mi = gbase + mm;
    KNN_INSERT_BL(d, mi)
  }
  float2* __restrict__ part = (float2*)(ws + OFF_PART);
  const int eb = r * 8;
  part[(eb + 0) * NQ + q] = make_float2(b0v, __int_as_float(i0v));
  part[(eb + 1) * NQ + q] = make_float2(b1v, __int_as_float(i1v));
  part[(eb + 2) * NQ + q] = make_float2(b2v, __int_as_float(i2v));
  part[(eb + 3) * NQ + q] = make_float2(b3v, __int_as_float(i3v));
  part[(eb + 4) * NQ + q] = make_float2(b4v, __int_as_float(i4v));
  part[(eb + 5) * NQ + q] = make_float2(b5v, __int_as_float(i5v));
  part[(eb + 6) * NQ + q] = make_float2(b6v, __int_as_float(i6v));
  part[(eb + 7) * NQ + q] = make_float2(b7v, __int_as_float(i7v));
}

__global__ __launch_bounds__(256) void knn_merge_kernel(float* __restrict__ ws) {
  const int q = blockIdx.x * 256 + threadIdx.x;  // 16384
  const float2* __restrict__ part = (const float2*)(ws + OFF_PART);
  float b0v = FMAXV, b1v = FMAXV, b2v = FMAXV, b3v = FMAXV,
        b4v = FMAXV, b5v = FMAXV, b6v = FMAXV, b7v = FMAXV;
  int i0v = 0, i1v = 0, i2v = 0, i3v = 0, i4v = 0, i5v = 0, i6v = 0, i7v = 0;
#pragma unroll 4
  for (int e = 0; e < 128; ++e) {
    const float2 en = part[(long)e * NQ + q];
    const float d = en.x;
    const int mi = __float_as_int(en.y);
    KNN_INSERT_BL(d, mi)
  }
  int* __restrict__ idxg = (int*)(ws + OFF_IDX);
  int* o = idxg + q * 8;
  o[0] = i0v; o[1] = i1v; o[2] = i2v; o[3] = i3v;
  o[4] = i4v; o[5] = i5v; o[6] = i6v; o[7] = i7v;
}

// ------------------------------- fused gemm --------------------------------
// chunk = 64 pairs (8 queries). 2048 chunks, 1 per block. 512 thr = 8 waves
// (wr = w>>2 in {0,1}: 32-pair half; wc = w&3: 32-fo slice).
// LDS 64KB: Ahi[64][128]bf16 @0 (16KB), Alo @16KB, H[64][128]u32 @32KB (32KB).
// OS (8q x 128f fp32, 4KB) aliases Ahi after g1 A-reads are done.
// A-plane 16B chunks swizzled col = kc ^ (row&7); H 16B chunks cc ^= (p&7).
__global__ __launch_bounds__(512, 4) void fused_kernel(float* __restrict__ ws,
                                                       float* __restrict__ out) {
  __shared__ char smem[65536];
  char* __restrict__ Ahi = smem;
  char* __restrict__ Alo = smem + 16384;
  unsigned* __restrict__ H = (unsigned*)(smem + 32768);
  float* __restrict__ OS = (float*)smem;

  const float* __restrict__ y = ws + OFF_Y;
  const int* __restrict__ idxg = (const int*)(ws + OFF_IDX);
  const unsigned* __restrict__ W1P = (const unsigned*)ws + OFF_W1F;
  const unsigned* __restrict__ W2P = (const unsigned*)ws + OFF_W2F;

  const int t = threadIdx.x;
  const int lane = t & 63, w = t >> 6;
  const int wr = w >> 2, wc = w & 3;
  const int bid = blockIdx.x;
  const int chunk = (bid & 7) * 256 + (bid >> 3);  // XCD-aligned: batch=bid&7

  // ---- stage A = h1 = relu(y_m - y_n + c0) -> bf16 hi/lo planes ----
  {
    const int row = t >> 3, part8 = t & 7;  // row: 64 pairs, part8: 16-elem slice
    const int gp = chunk * 64 + row;
    const int mg = idxg[gp];
    const float* __restrict__ ym = y + (long)mg * 128 + part8 * 16;
    const float* __restrict__ yn = y + (long)(gp >> 3) * 128 + part8 * 16;
    const float* __restrict__ c0 = ws + OFF_C0 + part8 * 16;
#pragma unroll
    for (int cj = 0; cj < 2; ++cj) {
      const float4 a0 = *(const float4*)(ym + cj * 8);
      const float4 a1 = *(const float4*)(ym + cj * 8 + 4);
      const float4 n0 = *(const float4*)(yn + cj * 8);
      const float4 n1 = *(const float4*)(yn + cj * 8 + 4);
      const float4 ca = *(const float4*)(c0 + cj * 8);
      const float4 cb = *(const float4*)(c0 + cj * 8 + 4);
      const float hv[8] = {
          relu_f(a0.x - n0.x + ca.x), relu_f(a0.y - n0.y + ca.y),
          relu_f(a0.z - n0.z + ca.z), relu_f(a0.w - n0.w + ca.w),
          relu_f(a1.x - n1.x + cb.x), relu_f(a1.y - n1.y + cb.y),
          relu_f(a1.z - n1.z + cb.z), relu_f(a1.w - n1.w + cb.w)};
      unsigned hh[8], ll[8];
#pragma unroll
      for (int e = 0; e < 8; ++e) split3(hv[e], hh[e], ll[e]);
      int4 hp, lp;
      hp.x = (int)(hh[0] | (hh[1] << 16));
      hp.y = (int)(hh[2] | (hh[3] << 16));
      hp.z = (int)(hh[4] | (hh[5] << 16));
      hp.w = (int)(hh[6] | (hh[7] << 16));
      lp.x = (int)(ll[0] | (ll[1] << 16));
      lp.y = (int)(ll[2] | (ll[3] << 16));
      lp.z = (int)(ll[4] | (ll[5] << 16));
      lp.w = (int)(ll[6] | (ll[7] << 16));
      const int kc = part8 * 2 + cj;
      const int col = kc ^ (row & 7);
      *(int4*)(Ahi + row * 256 + col * 16) = hp;
      *(int4*)(Alo + row * 256 + col * 16) = lp;
    }
  }
  __syncthreads();

  const float c1v0 = (ws + OFF_C1)[wc * 32 + (lane & 15)];
  const float c1v1 = (ws + OFF_C1)[wc * 32 + 16 + (lane & 15)];
  const float c2v0 = (ws + OFF_C2)[wc * 32 + (lane & 15)];
  const float c2v1 = (ws + OFF_C2)[wc * 32 + 16 + (lane & 15)];

  // ---- g1: acc = h1 . W1^T  (bf16x3) ----
  f32x4 acc[2][2];
#pragma unroll
  for (int pt = 0; pt < 2; ++pt)
#pragma unroll
    for (int ft = 0; ft < 2; ++ft) acc[pt][ft] = (f32x4){0.f, 0.f, 0.f, 0.f};

#pragma unroll 1
  for (int ks = 0; ks < 4; ++ks) {
    const int kb = ks * 32 + (lane >> 4) * 8;
    // W frags (streamed, L1-hot)
    short8v wh[2], wl[2];
#pragma unroll
    for (int ft = 0; ft < 2; ++ft) {
      const int fo = wc * 32 + ft * 16 + (lane & 15);
      const int4 u0 = *(const int4*)(W1P + fo * 128 + kb);
      const int4 u1 = *(const int4*)(W1P + fo * 128 + kb + 4);
      const unsigned uu[8] = {(unsigned)u0.x, (unsigned)u0.y, (unsigned)u0.z,
                              (unsigned)u0.w, (unsigned)u1.x, (unsigned)u1.y,
                              (unsigned)u1.z, (unsigned)u1.w};
      short8v h8, l8;
#pragma unroll
      for (int e = 0; e < 8; ++e) {
        h8[e] = (short)(uu[e] >> 16);
        l8[e] = (short)(uu[e] & 0xFFFFu);
      }
      wh[ft] = h8;
      wl[ft] = l8;
    }
    const int kc = ks * 4 + (lane >> 4);
#pragma unroll
    for (int pt = 0; pt < 2; ++pt) {
      const int row = wr * 32 + pt * 16 + (lane & 15);
      const int col = kc ^ (row & 7);
      const short8v ah = *(const short8v*)(Ahi + row * 256 + col * 16);
      const short8v al = *(const short8v*)(Alo + row * 256 + col * 16);
#pragma unroll
      for (int ft = 0; ft < 2; ++ft) {
        acc[pt][ft] = mfma16x16x32bf(al, wh[ft], acc[pt][ft]);
        acc[pt][ft] = mfma16x16x32bf(ah, wl[ft], acc[pt][ft]);
        acc[pt][ft] = mfma16x16x32bf(ah, wh[ft], acc[pt][ft]);
      }
    }
  }

  // ---- g1 epilogue: relu(acc+c1) -> H (packed u32, swizzled) ----
#pragma unroll
  for (int pt = 0; pt < 2; ++pt)
#pragma unroll
    for (int ft = 0; ft < 2; ++ft) {
      const int fo = wc * 32 + ft * 16 + (lane & 15);
      const int cc = fo >> 2;
      const float cb = ft ? c1v1 : c1v0;
#pragma unroll
      for (int reg = 0; reg < 4; ++reg) {
        const int p = wr * 32 + pt * 16 + (lane >> 4) * 4 + reg;
        const float vv = relu_f(acc[pt][ft][reg] + cb);
        unsigned hh, ll;
        split3(vv, hh, ll);
        H[p * 128 + ((cc ^ (p & 7)) << 2) + (fo & 3)] = (hh << 16) | ll;
      }
    }
  __syncthreads();

  // ---- g2: acc2 = h2 . W2^T  (bf16x3), A from H ----
  f32x4 acc2[2][2];
#pragma unroll
  for (int pt = 0; pt < 2; ++pt)
#pragma unroll
    for (int ft = 0; ft < 2; ++ft) acc2[pt][ft] = (f32x4){0.f, 0.f, 0.f, 0.f};

#pragma unroll 1
  for (int ks = 0; ks < 4; ++ks) {
    const int kb = ks * 32 + (lane >> 4) * 8;
    short8v wh[2], wl[2];
#pragma unroll
    for (int ft = 0; ft < 2; ++ft) {
      const int fo = wc * 32 + ft * 16 + (lane & 15);
      const int4 u0 = *(const int4*)(W2P + fo * 128 + kb);
      const int4 u1 = *(const int4*)(W2P + fo * 128 + kb + 4);
      const unsigned uu[8] = {(unsigned)u0.x, (unsigned)u0.y, (unsigned)u0.z,
                              (unsigned)u0.w, (unsigned)u1.x, (unsigned)u1.y,
                              (unsigned)u1.z, (unsigned)u1.w};
      short8v h8, l8;
#pragma unroll
      for (int e = 0; e < 8; ++e) {
        h8[e] = (short)(uu[e] >> 16);
        l8[e] = (short)(uu[e] & 0xFFFFu);
      }
      wh[ft] = h8;
      wl[ft] = l8;
    }
    const int cc0 = ks * 8 + (lane >> 4) * 2;
#pragma unroll
    for (int pt = 0; pt < 2; ++pt) {
      const int p = wr * 32 + pt * 16 + (lane & 15);
      const int4 u0 = *(const int4*)&H[p * 128 + ((cc0 ^ (p & 7)) << 2)];
      const int4 u1 = *(const int4*)&H[p * 128 + (((cc0 + 1) ^ (p & 7)) << 2)];
      const unsigned uu[8] = {(unsigned)u0.x, (unsigned)u0.y, (unsigned)u0.z,
                              (unsigned)u0.w, (unsigned)u1.x, (unsigned)u1.y,
                              (unsigned)u1.z, (unsigned)u1.w};
      short8v ah, al;
#pragma unroll
      for (int e = 0; e < 8; ++e) {
        ah[e] = (short)(uu[e] >> 16);
        al[e] = (short)(uu[e] & 0xFFFFu);
      }
#pragma unroll
      for (int ft = 0; ft < 2; ++ft) {
        acc2[pt][ft] = mfma16x16x32bf(al, wh[ft], acc2[pt][ft]);
        acc2[pt][ft] = mfma16x16x32bf(ah, wl[ft], acc2[pt][ft]);
        acc2[pt][ft] = mfma16x16x32bf(ah, wh[ft], acc2[pt][ft]);
      }
    }
  }

  // ---- g2 epilogue: relu(acc2+c2), max over 8 pairs/query -> OS[8][128] ----
  {
    const int g = lane >> 4;
#pragma unroll
    for (int pt = 0; pt < 2; ++pt)
#pragma unroll
      for (int ft = 0; ft < 2; ++ft) {
        const int fo = wc * 32 + ft * 16 + (lane & 15);
        const float cb = ft ? c2v1 : c2v0;
        const float v0 = relu_f(acc2[pt][ft][0] + cb);
        const float v1 = relu_f(acc2[pt][ft][1] + cb);
        const float v2 = relu_f(acc2[pt][ft][2] + cb);
        const float v3 = relu_f(acc2[pt][ft][3] + cb);
        float m = fmaxf(fmaxf(v0, v1), fmaxf(v2, v3));
        m = fmaxf(m, __shfl_xor(m, 16, 64));
        if ((g & 1) == 0) {
          const int qloc = wr * 4 + pt * 2 + (g >> 1);
          OS[qloc * 128 + fo] = m;
        }
      }
  }
  __syncthreads();

  // ---- coalesced transpose-out: out[b][f][n] ----
  {
    const int f = t >> 2, qg = t & 3;
    const int b = chunk >> 8, n0 = (chunk & 255) * 8;
    float2 o;
    o.x = OS[(qg * 2 + 0) * 128 + f];
    o.y = OS[(qg * 2 + 1) * 128 + f];
    *(float2*)(out + (long)(b * 128 + f) * 2048 + n0 + qg * 2) = o;
  }
}

// ------------------------------- launch ------------------------------------
extern "C" void kernel_launch(void* const* d_in, const int* in_sizes, int n_in,
                              void* d_out, int out_size, void* d_ws,
                              size_t ws_size, hipStream_t stream) {
  (void)in_sizes; (void)n_in; (void)out_size; (void)ws_size;
  const float* x = (const float*)d_in[0];
  const float* w0 = (const float*)d_in[1];
  const float* b0 = (const float*)d_in[2];
  const float* wst = (const float*)d_in[3];
  const float* bst = (const float*)d_in[4];
  const float* g = (const float*)d_in[5];
  const float* be = (const float*)d_in[6];
  const float* bm = (const float*)d_in[7];
  const float* bv = (const float*)d_in[8];
  float* out = (float*)d_out;
  float* ws = (float*)d_ws;

  prep_kernel<<<1, 256, 0, stream>>>(w0, b0, wst, bst, g, be, bm, bv, ws);
  y_kernel<<<NQ * DIMF / 256, 256, 0, stream>>>(x, ws);
  knn_part_kernel<<<1024, 256, 0, stream>>>(x, ws);
  knn_merge_kernel<<<NQ / 256, 256, 0, stream>>>(ws);
  fused_kernel<<<2048, 512, 0, stream>>>(ws, out);
}

// Round 5
// 165.862 us; speedup vs baseline: 2.0914x; 1.0333x over previous
//
#include <hip/hip_runtime.h>

// ---------------------------------------------------------------------------
// FeatureNet: kNN(K=8) relative grouping -> [conv1x1+BN+ReLU] x3 -> max over K
// B=8, N=2048, DIM=128, fp32 in/out.
//
// prep     : fold BN into weights/biases; W1/W2 as 4 bf16 planes (hi,lo)
// y        : y[q][f] = W0f . x[q]
// knn_part : 16 ranges x 128 candidates, branchless top-8, 1024 WGs
// knn_merge: merge 16 partial top-8 lists -> idx[q][8]
// fused    : per chunk of 64 pairs: h1 -> g1 MFMA -> H(LDS) -> g2 MFMA -> max
//            LDS = 32KB (H aliases A planes; OS aliases H) -> 4 blocks/CU.
//            XCD-aligned chunk mapping (batch == bid&7 == XCD round-robin).
//
// R4 bug fixed here: W planes end at FLOAT offset 32768 (65536 u16), but the
// scalar/y region started at float 16384 -> y overwrote W2 planes. Now the
// float-unit region starts at 32768.
// ---------------------------------------------------------------------------

#define EPSF 1e-5f
#define FMAXV 3.402823466e+38f

#define NB 8
#define NN 2048
#define KNBR 8
#define DIMF 128
#define NQ (NB * NN)        // 16384
#define NPAIR (NQ * KNBR)   // 131072

// ws layout. W planes in u16 units [0, 65536) == floats [0, 32768).
#define OFF16_W1H 0          // 16384 u16
#define OFF16_W1L 16384
#define OFF16_W2H 32768
#define OFF16_W2L 49152      // ends 65536 u16 = 32768 floats
#define OFF_C0 32768         // float units (byte 131072)
#define OFF_C1 32896
#define OFF_C2 33024
#define OFF_W0F 33152        // 384
#define OFF_Y 33792          // 2097152 floats
#define OFF_IDX (OFF_Y + NQ * DIMF)   // 131072 ints
#define OFF_PART (OFF_IDX + NPAIR)    // 16384*128*2 floats

typedef __attribute__((ext_vector_type(4))) float f32x4;
typedef __attribute__((ext_vector_type(8))) short short8v;

__device__ __forceinline__ float relu_f(float a) { return fmaxf(a, 0.0f); }

// fp32 -> bf16(hi, RNE) + bf16(lo, trunc of residual)
__device__ __forceinline__ void split3(float f, unsigned& hi, unsigned& lo) {
  const unsigned u = __float_as_uint(f);
  const unsigned h = (u + 0x7FFFu + ((u >> 16) & 1u)) >> 16;
  const float hf = __uint_as_float(h << 16);
  lo = __float_as_uint(f - hf) >> 16;
  hi = h;
}

__device__ __forceinline__ f32x4 mfma16x16x32bf(short8v a, short8v b, f32x4 c) {
  return __builtin_amdgcn_mfma_f32_16x16x32_bf16(a, b, c, 0, 0, 0);
}

// ------------------------------- prep --------------------------------------
__global__ __launch_bounds__(256) void prep_kernel(
    const float* __restrict__ w0, const float* __restrict__ b0,
    const float* __restrict__ wstk, const float* __restrict__ bstk,
    const float* __restrict__ g, const float* __restrict__ be,
    const float* __restrict__ bm, const float* __restrict__ bv,
    float* __restrict__ ws) {
  const int t = threadIdx.x;
  unsigned short* __restrict__ wsh = (unsigned short*)ws;
  for (int i = t; i < 16384; i += 256) {
    const int fo = i >> 7;
    const float s1 = g[128 + fo] / sqrtf(bv[128 + fo] + EPSF);
    const float s2 = g[256 + fo] / sqrtf(bv[256 + fo] + EPSF);
    unsigned h1, l1, h2, l2;
    split3(wstk[i] * s1, h1, l1);
    split3(wstk[16384 + i] * s2, h2, l2);
    wsh[OFF16_W1H + i] = (unsigned short)h1;
    wsh[OFF16_W1L + i] = (unsigned short)l1;
    wsh[OFF16_W2H + i] = (unsigned short)h2;
    wsh[OFF16_W2L + i] = (unsigned short)l2;
  }
  if (t < 128) {
    const int fo = t;
    const float s0 = g[fo] / sqrtf(bv[fo] + EPSF);
    const float s1 = g[128 + fo] / sqrtf(bv[128 + fo] + EPSF);
    const float s2 = g[256 + fo] / sqrtf(bv[256 + fo] + EPSF);
    ws[OFF_C0 + fo] = (b0[fo] - bm[fo]) * s0 + be[fo];
    ws[OFF_C1 + fo] = (bstk[fo] - bm[128 + fo]) * s1 + be[128 + fo];
    ws[OFF_C2 + fo] = (bstk[128 + fo] - bm[256 + fo]) * s2 + be[256 + fo];
    ws[OFF_W0F + 3 * fo + 0] = w0[3 * fo + 0] * s0;
    ws[OFF_W0F + 3 * fo + 1] = w0[3 * fo + 1] * s0;
    ws[OFF_W0F + 3 * fo + 2] = w0[3 * fo + 2] * s0;
  }
}

// ------------------------------- ycomp -------------------------------------
__global__ __launch_bounds__(256) void y_kernel(const float* __restrict__ x,
                                                float* __restrict__ ws) {
  const int gid = blockIdx.x * 256 + threadIdx.x;  // 2,097,152
  const int q = gid >> 7, f = gid & 127;
  const int b = q >> 11, n = q & 2047;
  const float* __restrict__ W0f = ws + OFF_W0F;
  const float w0 = W0f[f * 3 + 0], w1 = W0f[f * 3 + 1], w2 = W0f[f * 3 + 2];
  const float x0 = x[b * 6144 + n];
  const float x1 = x[b * 6144 + 2048 + n];
  const float x2 = x[b * 6144 + 4096 + n];
  ws[OFF_Y + gid] = fmaf(w2, x2, fmaf(w1, x1, w0 * x0));
}

// ------------------------------- knn ---------------------------------------
#define KNN_CSWAP(da, db, ia, ib)            \
  {                                          \
    const bool c_ = (db) < (da);             \
    const float lo_ = c_ ? (db) : (da);      \
    const float hi_ = c_ ? (da) : (db);      \
    const int il_ = c_ ? (ib) : (ia);        \
    const int ih_ = c_ ? (ia) : (ib);        \
    (da) = lo_; (db) = hi_;                  \
    (ia) = il_; (ib) = ih_;                  \
  }

#define KNN_INSERT_BL(d, mi)                  \
  {                                           \
    const bool cc_ = (d) < b7v;               \
    b7v = cc_ ? (d) : b7v;                    \
    i7v = cc_ ? (mi) : i7v;                   \
    KNN_CSWAP(b6v, b7v, i6v, i7v)             \
    KNN_CSWAP(b5v, b6v, i5v, i6v)             \
    KNN_CSWAP(b4v, b5v, i4v, i5v)             \
    KNN_CSWAP(b3v, b4v, i3v, i4v)             \
    KNN_CSWAP(b2v, b3v, i2v, i3v)             \
    KNN_CSWAP(b1v, b2v, i1v, i2v)             \
    KNN_CSWAP(b0v, b1v, i0v, i1v)             \
  }

// wg = qb*16 + r ; 256 threads = 256 queries; 128 candidates (range r)
__global__ __launch_bounds__(256) void knn_part_kernel(
    const float* __restrict__ x, float* __restrict__ ws) {
  __shared__ float4 xs4[128];
  const int t = threadIdx.x;
  const int wg = blockIdx.x;  // 1024
  const int qb = wg >> 4, r = wg & 15;
  const int b = qb >> 3;
  const float* __restrict__ xb = x + b * 3 * NN;
  if (t < 128) {
    const int i = r * 128 + t;
    const float a0 = xb[i];
    const float a1 = xb[2048 + i];
    const float a2 = xb[4096 + i];
    const float sq = fmaf(a2, a2, fmaf(a1, a1, a0 * a0));
    xs4[t] = make_float4(a0, a1, a2, sq);
  }
  __syncthreads();
  const int n = (qb & 7) * 256 + t;
  const int q = b * NN + n;
  const float qx0 = xb[n], qx1 = xb[2048 + n], qx2 = xb[4096 + n];
  const float sqn = fmaf(qx2, qx2, fmaf(qx1, qx1, qx0 * qx0));
  float b0v = FMAXV, b1v = FMAXV, b2v = FMAXV, b3v = FMAXV,
        b4v = FMAXV, b5v = FMAXV, b6v = FMAXV, b7v = FMAXV;
  int i0v = 0, i1v = 0, i2v = 0, i3v = 0, i4v = 0, i5v = 0, i6v = 0, i7v = 0;
  const int gbase = b * NN + r * 128;
#pragma unroll 4
  for (int mm = 0; mm < 128; ++mm) {
    const float4 c = xs4[mm];
    const float inner = fmaf(qx2, c.z, fmaf(qx1, c.y, qx0 * c.x));
    const float d = (sqn - 2.0f * inner) + c.w;
    const int mi = gbase + mm;
    KNN_INSERT_BL(d, mi)
  }
  float2* __restrict__ part = (float2*)(ws + OFF_PART);
  const int eb = r * 8;
  part[(eb + 0) * NQ + q] = make_float2(b0v, __int_as_float(i0v));
  part[(eb + 1) * NQ + q] = make_float2(b1v, __int_as_float(i1v));
  part[(eb + 2) * NQ + q] = make_float2(b2v, __int_as_float(i2v));
  part[(eb + 3) * NQ + q] = make_float2(b3v, __int_as_float(i3v));
  part[(eb + 4) * NQ + q] = make_float2(b4v, __int_as_float(i4v));
  part[(eb + 5) * NQ + q] = make_float2(b5v, __int_as_float(i5v));
  part[(eb + 6) * NQ + q] = make_float2(b6v, __int_as_float(i6v));
  part[(eb + 7) * NQ + q] = make_float2(b7v, __int_as_float(i7v));
}

__global__ __launch_bounds__(64) void knn_merge_kernel(float* __restrict__ ws) {
  const int q = blockIdx.x * 64 + threadIdx.x;  // 16384
  const float2* __restrict__ part = (const float2*)(ws + OFF_PART);
  float b0v = FMAXV, b1v = FMAXV, b2v = FMAXV, b3v = FMAXV,
        b4v = FMAXV, b5v = FMAXV, b6v = FMAXV, b7v = FMAXV;
  int i0v = 0, i1v = 0, i2v = 0, i3v = 0, i4v = 0, i5v = 0, i6v = 0, i7v = 0;
#pragma unroll 8
  for (int e = 0; e < 128; ++e) {
    const float2 en = part[(long)e * NQ + q];
    const float d = en.x;
    const int mi = __float_as_int(en.y);
    KNN_INSERT_BL(d, mi)
  }
  int* __restrict__ idxg = (int*)(ws + OFF_IDX);
  int* o = idxg + q * 8;
  o[0] = i0v; o[1] = i1v; o[2] = i2v; o[3] = i3v;
  o[4] = i4v; o[5] = i5v; o[6] = i6v; o[7] = i7v;
}

// ------------------------------- fused gemm --------------------------------
// chunk = 64 pairs (8 queries). 2048 chunks, 1 per block. 512 thr = 8 waves
// (wr = w>>2 in {0,1}: 32-pair half; wc = w&3: 32-fo slice).
// LDS 32KB: Ahi[64][128]bf16 @0 (16KB), Alo @16KB.
//           H[64][128]u32 (32KB) ALIASES Ahi+Alo (g1 consumed A first).
//           OS[8][128]f32 (4KB) aliases H after g2 consumed it.
// A-plane 16B chunks swizzled col = kc ^ (row&7); H 16B chunks cc ^= (p&7).
__global__ __launch_bounds__(512, 8) void fused_kernel(float* __restrict__ ws,
                                                       float* __restrict__ out) {
  __shared__ char smem[32768];
  char* __restrict__ Ahi = smem;
  char* __restrict__ Alo = smem + 16384;
  unsigned* __restrict__ H = (unsigned*)smem;
  float* __restrict__ OS = (float*)smem;

  const float* __restrict__ y = ws + OFF_Y;
  const int* __restrict__ idxg = (const int*)(ws + OFF_IDX);
  const unsigned short* __restrict__ W1Hp = (const unsigned short*)ws + OFF16_W1H;
  const unsigned short* __restrict__ W1Lp = (const unsigned short*)ws + OFF16_W1L;
  const unsigned short* __restrict__ W2Hp = (const unsigned short*)ws + OFF16_W2H;
  const unsigned short* __restrict__ W2Lp = (const unsigned short*)ws + OFF16_W2L;

  const int t = threadIdx.x;
  const int lane = t & 63, w = t >> 6;
  const int wr = w >> 2, wc = w & 3;
  const int bid = blockIdx.x;
  const int chunk = (bid & 7) * 256 + (bid >> 3);  // XCD-aligned: batch=bid&7

  // ---- stage A = h1 = relu(y_m - y_n + c0) -> bf16 hi/lo planes ----
  {
    const int row = t >> 3, part8 = t & 7;
    const int gp = chunk * 64 + row;
    const int mg = idxg[gp];
    const float* __restrict__ ym = y + (long)mg * 128 + part8 * 16;
    const float* __restrict__ yn = y + (long)(gp >> 3) * 128 + part8 * 16;
    const float* __restrict__ c0 = ws + OFF_C0 + part8 * 16;
#pragma unroll
    for (int cj = 0; cj < 2; ++cj) {
      const float4 a0 = *(const float4*)(ym + cj * 8);
      const float4 a1 = *(const float4*)(ym + cj * 8 + 4);
      const float4 n0 = *(const float4*)(yn + cj * 8);
      const float4 n1 = *(const float4*)(yn + cj * 8 + 4);
      const float4 ca = *(const float4*)(c0 + cj * 8);
      const float4 cb = *(const float4*)(c0 + cj * 8 + 4);
      const float hv[8] = {
          relu_f(a0.x - n0.x + ca.x), relu_f(a0.y - n0.y + ca.y),
          relu_f(a0.z - n0.z + ca.z), relu_f(a0.w - n0.w + ca.w),
          relu_f(a1.x - n1.x + cb.x), relu_f(a1.y - n1.y + cb.y),
          relu_f(a1.z - n1.z + cb.z), relu_f(a1.w - n1.w + cb.w)};
      unsigned hh[8], ll[8];
#pragma unroll
      for (int e = 0; e < 8; ++e) split3(hv[e], hh[e], ll[e]);
      int4 hp, lp;
      hp.x = (int)(hh[0] | (hh[1] << 16));
      hp.y = (int)(hh[2] | (hh[3] << 16));
      hp.z = (int)(hh[4] | (hh[5] << 16));
      hp.w = (int)(hh[6] | (hh[7] << 16));
      lp.x = (int)(ll[0] | (ll[1] << 16));
      lp.y = (int)(ll[2] | (ll[3] << 16));
      lp.z = (int)(ll[4] | (ll[5] << 16));
      lp.w = (int)(ll[6] | (ll[7] << 16));
      const int kc = part8 * 2 + cj;
      const int col = kc ^ (row & 7);
      *(int4*)(Ahi + row * 256 + col * 16) = hp;
      *(int4*)(Alo + row * 256 + col * 16) = lp;
    }
  }
  __syncthreads();

  const float c1v0 = (ws + OFF_C1)[wc * 32 + (lane & 15)];
  const float c1v1 = (ws + OFF_C1)[wc * 32 + 16 + (lane & 15)];
  const float c2v0 = (ws + OFF_C2)[wc * 32 + (lane & 15)];
  const float c2v1 = (ws + OFF_C2)[wc * 32 + 16 + (lane & 15)];

  // ---- g1: acc = h1 . W1^T  (bf16x3) ----
  f32x4 acc[2][2];
#pragma unroll
  for (int pt = 0; pt < 2; ++pt)
#pragma unroll
    for (int ft = 0; ft < 2; ++ft) acc[pt][ft] = (f32x4){0.f, 0.f, 0.f, 0.f};

#pragma unroll 1
  for (int ks = 0; ks < 4; ++ks) {
    const int kb = ks * 32 + (lane >> 4) * 8;
    short8v wh[2], wl[2];
#pragma unroll
    for (int ft = 0; ft < 2; ++ft) {
      const int fo = wc * 32 + ft * 16 + (lane & 15);
      wh[ft] = *(const short8v*)(W1Hp + fo * 128 + kb);
      wl[ft] = *(const short8v*)(W1Lp + fo * 128 + kb);
    }
    const int kc = ks * 4 + (lane >> 4);
#pragma unroll
    for (int pt = 0; pt < 2; ++pt) {
      const int row = wr * 32 + pt * 16 + (lane & 15);
      const int col = kc ^ (row & 7);
      const short8v ah = *(const short8v*)(Ahi + row * 256 + col * 16);
      const short8v al = *(const short8v*)(Alo + row * 256 + col * 16);
#pragma unroll
      for (int ft = 0; ft < 2; ++ft) {
        acc[pt][ft] = mfma16x16x32bf(al, wh[ft], acc[pt][ft]);
        acc[pt][ft] = mfma16x16x32bf(ah, wl[ft], acc[pt][ft]);
        acc[pt][ft] = mfma16x16x32bf(ah, wh[ft], acc[pt][ft]);
      }
    }
  }
  __syncthreads();  // all A reads complete before H overwrites the planes

  // ---- g1 epilogue: relu(acc+c1) -> H (packed u32, swizzled, aliases A) ----
#pragma unroll
  for (int pt = 0; pt < 2; ++pt)
#pragma unroll
    for (int ft = 0; ft < 2; ++ft) {
      const int fo = wc * 32 + ft * 16 + (lane & 15);
      const int cc = fo >> 2;
      const float cb = ft ? c1v1 : c1v0;
#pragma unroll
      for (int reg = 0; reg < 4; ++reg) {
        const int p = wr * 32 + pt * 16 + (lane >> 4) * 4 + reg;
        const float vv = relu_f(acc[pt][ft][reg] + cb);
        unsigned hh, ll;
        split3(vv, hh, ll);
        H[p * 128 + ((cc ^ (p & 7)) << 2) + (fo & 3)] = (hh << 16) | ll;
      }
    }
  __syncthreads();

  // ---- g2: acc2 = h2 . W2^T  (bf16x3), A from H ----
  f32x4 acc2[2][2];
#pragma unroll
  for (int pt = 0; pt < 2; ++pt)
#pragma unroll
    for (int ft = 0; ft < 2; ++ft) acc2[pt][ft] = (f32x4){0.f, 0.f, 0.f, 0.f};

#pragma unroll 1
  for (int ks = 0; ks < 4; ++ks) {
    const int kb = ks * 32 + (lane >> 4) * 8;
    short8v wh[2], wl[2];
#pragma unroll
    for (int ft = 0; ft < 2; ++ft) {
      const int fo = wc * 32 + ft * 16 + (lane & 15);
      wh[ft] = *(const short8v*)(W2Hp + fo * 128 + kb);
      wl[ft] = *(const short8v*)(W2Lp + fo * 128 + kb);
    }
    const int cc0 = ks * 8 + (lane >> 4) * 2;
#pragma unroll
    for (int pt = 0; pt < 2; ++pt) {
      const int p = wr * 32 + pt * 16 + (lane & 15);
      const int4 u0 = *(const int4*)&H[p * 128 + ((cc0 ^ (p & 7)) << 2)];
      const int4 u1 = *(const int4*)&H[p * 128 + (((cc0 + 1) ^ (p & 7)) << 2)];
      const unsigned uu[8] = {(unsigned)u0.x, (unsigned)u0.y, (unsigned)u0.z,
                              (unsigned)u0.w, (unsigned)u1.x, (unsigned)u1.y,
                              (unsigned)u1.z, (unsigned)u1.w};
      short8v ah, al;
#pragma unroll
      for (int e = 0; e < 8; ++e) {
        ah[e] = (short)(uu[e] >> 16);
        al[e] = (short)(uu[e] & 0xFFFFu);
      }
#pragma unroll
      for (int ft = 0; ft < 2; ++ft) {
        acc2[pt][ft] = mfma16x16x32bf(al, wh[ft], acc2[pt][ft]);
        acc2[pt][ft] = mfma16x16x32bf(ah, wl[ft], acc2[pt][ft]);
        acc2[pt][ft] = mfma16x16x32bf(ah, wh[ft], acc2[pt][ft]);
      }
    }
  }
  __syncthreads();  // all H reads complete before OS overwrites

  // ---- g2 epilogue: relu(acc2+c2), max over 8 pairs/query -> OS[8][128] ----
  {
    const int g = lane >> 4;
#pragma unroll
    for (int pt = 0; pt < 2; ++pt)
#pragma unroll
      for (int ft = 0; ft < 2; ++ft) {
        const int fo = wc * 32 + ft * 16 + (lane & 15);
        const float cb = ft ? c2v1 : c2v0;
        const float v0 = relu_f(acc2[pt][ft][0] + cb);
        const float v1 = relu_f(acc2[pt][ft][1] + cb);
        const float v2 = relu_f(acc2[pt][ft][2] + cb);
        const float v3 = relu_f(acc2[pt][ft][3] + cb);
        float m = fmaxf(fmaxf(v0, v1), fmaxf(v2, v3));
        m = fmaxf(m, __shfl_xor(m, 16, 64));
        if ((g & 1) == 0) {
          const int qloc = wr * 4 + pt * 2 + (g >> 1);
          OS[qloc * 128 + fo] = m;
        }
      }
  }
  __syncthreads();

  // ---- coalesced transpose-out: out[b][f][n] ----
  {
    const int f = t >> 2, qg = t & 3;
    const int b = chunk >> 8, n0 = (chunk & 255) * 8;
    float2 o;
    o.x = OS[(qg * 2 + 0) * 128 + f];
    o.y = OS[(qg * 2 + 1) * 128 + f];
    *(float2*)(out + (long)(b * 128 + f) * 2048 + n0 + qg * 2) = o;
  }
}

// ------------------------------- launch ------------------------------------
extern "C" void kernel_launch(void* const* d_in, const int* in_sizes, int n_in,
                              void* d_out, int out_size, void* d_ws,
                              size_t ws_size, hipStream_t stream) {
  (void)in_sizes; (void)n_in; (void)out_size; (void)ws_size;
  const float* x = (const float*)d_in[0];
  const float* w0 = (const float*)d_in[1];
  const float* b0 = (const float*)d_in[2];
  const float* wst = (const float*)d_in[3];
  const float* bst = (const float*)d_in[4];
  const float* g = (const float*)d_in[5];
  const float* be = (const float*)d_in[6];
  const float* bm = (const float*)d_in[7];
  const float* bv = (const float*)d_in[8];
  float* out = (float*)d_out;
  float* ws = (float*)d_ws;

  prep_kernel<<<1, 256, 0, stream>>>(w0, b0, wst, bst, g, be, bm, bv, ws);
  y_kernel<<<NQ * DIMF / 256, 256, 0, stream>>>(x, ws);
  knn_part_kernel<<<1024, 256, 0, stream>>>(x, ws);
  knn_merge_kernel<<<NQ / 64, 64, 0, stream>>>(ws);
  fused_kernel<<<2048, 512, 0, stream>>>(ws, out);
}

// Round 6
// 110.794 us; speedup vs baseline: 3.1308x; 1.4970x over previous
//
#include <hip/hip_runtime.h>

// ---------------------------------------------------------------------------
// FeatureNet: kNN(K=8) relative grouping -> [conv1x1+BN+ReLU] x3 -> max over K
// B=8, N=2048, DIM=128, fp32 in/out.
//
// prep     : fold BN; W1/W2 stored as 4 bf16 planes in MFMA FRAGMENT ORDER
// y        : y[q][f] = W0f . x[q]
// knn_part : 16 ranges x 128 candidates, branchless top-8, 1024 WGs
// knn_merge: merge 16 partial top-8 lists -> idx[q][8]
// fused    : PERSISTENT: 256 blocks (1/CU), 8 chunks each, W in 128 VGPRs
//            (loaded once, coalesced frag-order). A double-buffered in LDS,
//            H own region, OS accumulated and written coalesced at end.
//            XCD-aligned: block bid -> batch bid&7 (1MB y slice per XCD L2).
// ---------------------------------------------------------------------------

#define EPSF 1e-5f
#define FMAXV 3.402823466e+38f

#define NB 8
#define NN 2048
#define KNBR 8
#define DIMF 128
#define NQ (NB * NN)        // 16384
#define NPAIR (NQ * KNBR)   // 131072

// ws layout. W planes in u16 units [0, 65536) == floats [0, 32768).
#define OFF16_W1H 0          // 16384 u16 (fragment order)
#define OFF16_W1L 16384
#define OFF16_W2H 32768
#define OFF16_W2L 49152
#define OFF_C0 32768         // float units
#define OFF_C1 32896
#define OFF_C2 33024
#define OFF_W0F 33152        // 384
#define OFF_Y 33792          // 2097152 floats
#define OFF_IDX (OFF_Y + NQ * DIMF)   // 131072 ints
#define OFF_PART (OFF_IDX + NPAIR)    // 16384*128*2 floats

typedef __attribute__((ext_vector_type(4))) float f32x4;
typedef __attribute__((ext_vector_type(8))) short short8v;

__device__ __forceinline__ float relu_f(float a) { return fmaxf(a, 0.0f); }

// fp32 -> bf16(hi, RNE) + bf16(lo, trunc of residual)
__device__ __forceinline__ void split3(float f, unsigned& hi, unsigned& lo) {
  const unsigned u = __float_as_uint(f);
  const unsigned h = (u + 0x7FFFu + ((u >> 16) & 1u)) >> 16;
  const float hf = __uint_as_float(h << 16);
  lo = __float_as_uint(f - hf) >> 16;
  hi = h;
}

__device__ __forceinline__ f32x4 mfma16x16x32bf(short8v a, short8v b, f32x4 c) {
  return __builtin_amdgcn_mfma_f32_16x16x32_bf16(a, b, c, 0, 0, 0);
}

// ------------------------------- prep --------------------------------------
// grid 64 x 256. Fragment-order W store:
//   (fo,k) -> tile=(fo>>4)*4+(k>>5), lane=((k>>3)&3)*16+(fo&15), e=k&7
//   dst = tile*512 + lane*8 + e   (so a wave's frag load = contiguous 1KB)
__global__ __launch_bounds__(256) void prep_kernel(
    const float* __restrict__ w0, const float* __restrict__ b0,
    const float* __restrict__ wstk, const float* __restrict__ bstk,
    const float* __restrict__ g, const float* __restrict__ be,
    const float* __restrict__ bm, const float* __restrict__ bv,
    float* __restrict__ ws) {
  const int i = blockIdx.x * 256 + threadIdx.x;  // 16384
  unsigned short* __restrict__ wsh = (unsigned short*)ws;
  {
    const int fo = i >> 7, k = i & 127;
    const float s1 = g[128 + fo] / sqrtf(bv[128 + fo] + EPSF);
    const float s2 = g[256 + fo] / sqrtf(bv[256 + fo] + EPSF);
    unsigned h1, l1, h2, l2;
    split3(wstk[i] * s1, h1, l1);
    split3(wstk[16384 + i] * s2, h2, l2);
    const int dst = ((fo >> 4) * 4 + (k >> 5)) * 512 +
                    (((k >> 3) & 3) * 16 + (fo & 15)) * 8 + (k & 7);
    wsh[OFF16_W1H + dst] = (unsigned short)h1;
    wsh[OFF16_W1L + dst] = (unsigned short)l1;
    wsh[OFF16_W2H + dst] = (unsigned short)h2;
    wsh[OFF16_W2L + dst] = (unsigned short)l2;
  }
  if (blockIdx.x == 0 && threadIdx.x < 128) {
    const int fo = threadIdx.x;
    const float s0 = g[fo] / sqrtf(bv[fo] + EPSF);
    const float s1 = g[128 + fo] / sqrtf(bv[128 + fo] + EPSF);
    const float s2 = g[256 + fo] / sqrtf(bv[256 + fo] + EPSF);
    ws[OFF_C0 + fo] = (b0[fo] - bm[fo]) * s0 + be[fo];
    ws[OFF_C1 + fo] = (bstk[fo] - bm[128 + fo]) * s1 + be[128 + fo];
    ws[OFF_C2 + fo] = (bstk[128 + fo] - bm[256 + fo]) * s2 + be[256 + fo];
    ws[OFF_W0F + 3 * fo + 0] = w0[3 * fo + 0] * s0;
    ws[OFF_W0F + 3 * fo + 1] = w0[3 * fo + 1] * s0;
    ws[OFF_W0F + 3 * fo + 2] = w0[3 * fo + 2] * s0;
  }
}

// ------------------------------- ycomp -------------------------------------
__global__ __launch_bounds__(256) void y_kernel(const float* __restrict__ x,
                                                float* __restrict__ ws) {
  const int gid = blockIdx.x * 256 + threadIdx.x;  // 2,097,152
  const int q = gid >> 7, f = gid & 127;
  const int b = q >> 11, n = q & 2047;
  const float* __restrict__ W0f = ws + OFF_W0F;
  const float w0 = W0f[f * 3 + 0], w1 = W0f[f * 3 + 1], w2 = W0f[f * 3 + 2];
  const float x0 = x[b * 6144 + n];
  const float x1 = x[b * 6144 + 2048 + n];
  const float x2 = x[b * 6144 + 4096 + n];
  ws[OFF_Y + gid] = fmaf(w2, x2, fmaf(w1, x1, w0 * x0));
}

// ------------------------------- knn ---------------------------------------
#define KNN_CSWAP(da, db, ia, ib)            \
  {                                          \
    const bool c_ = (db) < (da);             \
    const float lo_ = c_ ? (db) : (da);      \
    const float hi_ = c_ ? (da) : (db);      \
    const int il_ = c_ ? (ib) : (ia);        \
    const int ih_ = c_ ? (ia) : (ib);        \
    (da) = lo_; (db) = hi_;                  \
    (ia) = il_; (ib) = ih_;                  \
  }

#define KNN_INSERT_BL(d, mi)                  \
  {                                           \
    const bool cc_ = (d) < b7v;               \
    b7v = cc_ ? (d) : b7v;                    \
    i7v = cc_ ? (mi) : i7v;                   \
    KNN_CSWAP(b6v, b7v, i6v, i7v)             \
    KNN_CSWAP(b5v, b6v, i5v, i6v)             \
    KNN_CSWAP(b4v, b5v, i4v, i5v)             \
    KNN_CSWAP(b3v, b4v, i3v, i4v)             \
    KNN_CSWAP(b2v, b3v, i2v, i3v)             \
    KNN_CSWAP(b1v, b2v, i1v, i2v)             \
    KNN_CSWAP(b0v, b1v, i0v, i1v)             \
  }

// wg = qb*16 + r ; 256 threads = 256 queries; 128 candidates (range r)
__global__ __launch_bounds__(256) void knn_part_kernel(
    const float* __restrict__ x, float* __restrict__ ws) {
  __shared__ float4 xs4[128];
  const int t = threadIdx.x;
  const int wg = blockIdx.x;  // 1024
  const int qb = wg >> 4, r = wg & 15;
  const int b = qb >> 3;
  const float* __restrict__ xb = x + b * 3 * NN;
  if (t < 128) {
    const int i = r * 128 + t;
    const float a0 = xb[i];
    const float a1 = xb[2048 + i];
    const float a2 = xb[4096 + i];
    const float sq = fmaf(a2, a2, fmaf(a1, a1, a0 * a0));
    xs4[t] = make_float4(a0, a1, a2, sq);
  }
  __syncthreads();
  const int n = (qb & 7) * 256 + t;
  const int q = b * NN + n;
  const float qx0 = xb[n], qx1 = xb[2048 + n], qx2 = xb[4096 + n];
  const float sqn = fmaf(qx2, qx2, fmaf(qx1, qx1, qx0 * qx0));
  float b0v = FMAXV, b1v = FMAXV, b2v = FMAXV, b3v = FMAXV,
        b4v = FMAXV, b5v = FMAXV, b6v = FMAXV, b7v = FMAXV;
  int i0v = 0, i1v = 0, i2v = 0, i3v = 0, i4v = 0, i5v = 0, i6v = 0, i7v = 0;
  const int gbase = b * NN + r * 128;
#pragma unroll 4
  for (int mm = 0; mm < 128; ++mm) {
    const float4 c = xs4[mm];
    const float inner = fmaf(qx2, c.z, fmaf(qx1, c.y, qx0 * c.x));
    const float d = (sqn - 2.0f * inner) + c.w;
    const int mi = gbase + mm;
    KNN_INSERT_BL(d, mi)
  }
  float2* __restrict__ part = (float2*)(ws + OFF_PART);
  const int eb = r * 8;
  part[(eb + 0) * NQ + q] = make_float2(b0v, __int_as_float(i0v));
  part[(eb + 1) * NQ + q] = make_float2(b1v, __int_as_float(i1v));
  part[(eb + 2) * NQ + q] = make_float2(b2v, __int_as_float(i2v));
  part[(eb + 3) * NQ + q] = make_float2(b3v, __int_as_float(i3v));
  part[(eb + 4) * NQ + q] = make_float2(b4v, __int_as_float(i4v));
  part[(eb + 5) * NQ + q] = make_float2(b5v, __int_as_float(i5v));
  part[(eb + 6) * NQ + q] = make_float2(b6v, __int_as_float(i6v));
  part[(eb + 7) * NQ + q] = make_float2(b7v, __int_as_float(i7v));
}

__global__ __launch_bounds__(64) void knn_merge_kernel(float* __restrict__ ws) {
  const int q = blockIdx.x * 64 + threadIdx.x;  // 16384
  const float2* __restrict__ part = (const float2*)(ws + OFF_PART);
  float b0v = FMAXV, b1v = FMAXV, b2v = FMAXV, b3v = FMAXV,
        b4v = FMAXV, b5v = FMAXV, b6v = FMAXV, b7v = FMAXV;
  int i0v = 0, i1v = 0, i2v = 0, i3v = 0, i4v = 0, i5v = 0, i6v = 0, i7v = 0;
#pragma unroll 8
  for (int e = 0; e < 128; ++e) {
    const float2 en = part[(long)e * NQ + q];
    const float d = en.x;
    const int mi = __float_as_int(en.y);
    KNN_INSERT_BL(d, mi)
  }
  int* __restrict__ idxg = (int*)(ws + OFF_IDX);
  int* o = idxg + q * 8;
  o[0] = i0v; o[1] = i1v; o[2] = i2v; o[3] = i3v;
  o[4] = i4v; o[5] = i5v; o[6] = i6v; o[7] = i7v;
}

// --------------------------- persistent fused ------------------------------
// 256 blocks x 512 thr (8 waves: wr=w>>2 pair-half, wc=w&3 fo-slice).
// Block bid: batch bb=bid&7, queries qseg*64..+64 (qseg=bid>>3), 8 chunks of
// 64 pairs. LDS 128KB: A dbuf 2x32KB @0, H 32KB @64K, OS 32KB @96K.
// A-plane 16B chunks swizzled col = kc ^ (row&7); H 16B chunks cc ^= (p&7).
__global__ __launch_bounds__(512, 2) void fused_kernel(float* __restrict__ ws,
                                                       float* __restrict__ out) {
  extern __shared__ char smem[];
  unsigned* __restrict__ H = (unsigned*)(smem + 65536);
  float* __restrict__ OS = (float*)(smem + 98304);

  const float* __restrict__ y = ws + OFF_Y;
  const int* __restrict__ idxg = (const int*)(ws + OFF_IDX);
  const unsigned short* __restrict__ wsu = (const unsigned short*)ws;

  const int t = threadIdx.x;
  const int lane = t & 63, w = t >> 6;
  const int wr = w >> 2, wc = w & 3;
  const int bid = blockIdx.x;
  const int bb = bid & 7, qseg = bid >> 3;
  const int chunk0 = bb * 256 + qseg * 8;

  // ---- W fragments -> registers (once; coalesced 1KB/wave frag loads) ----
  short8v w1h[2][4], w1l[2][4], w2h[2][4], w2l[2][4];
#pragma unroll
  for (int ft = 0; ft < 2; ++ft)
#pragma unroll
    for (int ks = 0; ks < 4; ++ks) {
      const int off = ((wc * 2 + ft) * 4 + ks) * 512 + lane * 8;
      w1h[ft][ks] = *(const short8v*)(wsu + OFF16_W1H + off);
      w1l[ft][ks] = *(const short8v*)(wsu + OFF16_W1L + off);
      w2h[ft][ks] = *(const short8v*)(wsu + OFF16_W2H + off);
      w2l[ft][ks] = *(const short8v*)(wsu + OFF16_W2L + off);
    }

  const float c1v0 = (ws + OFF_C1)[wc * 32 + (lane & 15)];
  const float c1v1 = (ws + OFF_C1)[wc * 32 + 16 + (lane & 15)];
  const float c2v0 = (ws + OFF_C2)[wc * 32 + (lane & 15)];
  const float c2v1 = (ws + OFF_C2)[wc * 32 + 16 + (lane & 15)];

  // ---- per-thread A-staging constants ----
  const int row = t >> 3, part8 = t & 7;
  const float* __restrict__ c0p = ws + OFF_C0 + part8 * 16;
  const float4 c0a = *(const float4*)(c0p + 0);
  const float4 c0b = *(const float4*)(c0p + 4);
  const float4 c0c = *(const float4*)(c0p + 8);
  const float4 c0d = *(const float4*)(c0p + 12);

// pack 8 floats (relu'd h1 values) into hi/lo int4 and write swizzled
#define PACK_WRITE_A(base, hv, kc)                              \
  {                                                             \
    unsigned hh[8], ll[8];                                      \
    _Pragma("unroll") for (int e = 0; e < 8; ++e)               \
        split3(hv[e], hh[e], ll[e]);                            \
    int4 hp, lp;                                                \
    hp.x = (int)(hh[0] | (hh[1] << 16));                        \
    hp.y = (int)(hh[2] | (hh[3] << 16));                        \
    hp.z = (int)(hh[4] | (hh[5] << 16));                        \
    hp.w = (int)(hh[6] | (hh[7] << 16));                        \
    lp.x = (int)(ll[0] | (ll[1] << 16));                        \
    lp.y = (int)(ll[2] | (ll[3] << 16));                        \
    lp.z = (int)(ll[4] | (ll[5] << 16));                        \
    lp.w = (int)(ll[6] | (ll[7] << 16));                        \
    const int col = (kc) ^ (row & 7);                           \
    *(int4*)((base) + row * 256 + col * 16) = hp;               \
    *(int4*)((base) + 16384 + row * 256 + col * 16) = lp;       \
  }

  // ---- prologue: stage A[0] into buf0 ----
  {
    const int gp = chunk0 * 64 + row;
    const int mg = idxg[gp];
    const float* __restrict__ ym = y + (long)mg * 128 + part8 * 16;
    const float* __restrict__ yn = y + (long)(gp >> 3) * 128 + part8 * 16;
    const float4 a0 = *(const float4*)(ym + 0);
    const float4 a1 = *(const float4*)(ym + 4);
    const float4 a2 = *(const float4*)(ym + 8);
    const float4 a3 = *(const float4*)(ym + 12);
    const float4 n0 = *(const float4*)(yn + 0);
    const float4 n1 = *(const float4*)(yn + 4);
    const float4 n2 = *(const float4*)(yn + 8);
    const float4 n3 = *(const float4*)(yn + 12);
    float hv0[8] = {relu_f(a0.x - n0.x + c0a.x), relu_f(a0.y - n0.y + c0a.y),
                    relu_f(a0.z - n0.z + c0a.z), relu_f(a0.w - n0.w + c0a.w),
                    relu_f(a1.x - n1.x + c0b.x), relu_f(a1.y - n1.y + c0b.y),
                    relu_f(a1.z - n1.z + c0b.z), relu_f(a1.w - n1.w + c0b.w)};
    float hv1[8] = {relu_f(a2.x - n2.x + c0c.x), relu_f(a2.y - n2.y + c0c.y),
                    relu_f(a2.z - n2.z + c0c.z), relu_f(a2.w - n2.w + c0c.w),
                    relu_f(a3.x - n3.x + c0d.x), relu_f(a3.y - n3.y + c0d.y),
                    relu_f(a3.z - n3.z + c0d.z), relu_f(a3.w - n3.w + c0d.w)};
    PACK_WRITE_A(smem, hv0, part8 * 2)
    PACK_WRITE_A(smem, hv1, part8 * 2 + 1)
  }
  __syncthreads();

#pragma unroll 1
  for (int j = 0; j < 8; ++j) {
    char* __restrict__ Acur = smem + (j & 1) * 32768;
    char* __restrict__ Anxt = smem + ((j & 1) ^ 1) * 32768;

    // issue next chunk's idx early (independent of g1)
    int mg_next = 0, gp_next = 0;
    if (j < 7) {
      gp_next = (chunk0 + j + 1) * 64 + row;
      mg_next = idxg[gp_next];
    }

    // ---- g1: acc = h1 . W1^T (bf16x3), A from Acur ----
    f32x4 acc[2][2];
#pragma unroll
    for (int pt = 0; pt < 2; ++pt)
#pragma unroll
      for (int ft = 0; ft < 2; ++ft) acc[pt][ft] = (f32x4){0.f, 0.f, 0.f, 0.f};
#pragma unroll
    for (int ks = 0; ks < 4; ++ks) {
      const int kc = ks * 4 + (lane >> 4);
#pragma unroll
      for (int pt = 0; pt < 2; ++pt) {
        const int arow = wr * 32 + pt * 16 + (lane & 15);
        const int col = kc ^ (arow & 7);
        const short8v ah = *(const short8v*)(Acur + arow * 256 + col * 16);
        const short8v al =
            *(const short8v*)(Acur + 16384 + arow * 256 + col * 16);
#pragma unroll
        for (int ft = 0; ft < 2; ++ft) {
          acc[pt][ft] = mfma16x16x32bf(al, w1h[ft][ks], acc[pt][ft]);
          acc[pt][ft] = mfma16x16x32bf(ah, w1l[ft][ks], acc[pt][ft]);
          acc[pt][ft] = mfma16x16x32bf(ah, w1h[ft][ks], acc[pt][ft]);
        }
      }
    }

    // ---- issue next chunk's y loads (latency hides under H + g2) ----
    float4 a0, a1, a2, a3, n0, n1, n2, n3;
    if (j < 7) {
      const float* __restrict__ ym = y + (long)mg_next * 128 + part8 * 16;
      const float* __restrict__ yn = y + (long)(gp_next >> 3) * 128 + part8 * 16;
      a0 = *(const float4*)(ym + 0);
      a1 = *(const float4*)(ym + 4);
      a2 = *(const float4*)(ym + 8);
      a3 = *(const float4*)(ym + 12);
      n0 = *(const float4*)(yn + 0);
      n1 = *(const float4*)(yn + 4);
      n2 = *(const float4*)(yn + 8);
      n3 = *(const float4*)(yn + 12);
    }

    // ---- g1 epilogue: relu(acc+c1) -> H (packed u32, swizzled) ----
    // (H free: previous iteration's g2 reads completed before last barrier)
#pragma unroll
    for (int pt = 0; pt < 2; ++pt)
#pragma unroll
      for (int ft = 0; ft < 2; ++ft) {
        const int fo = wc * 32 + ft * 16 + (lane & 15);
        const int cc = fo >> 2;
        const float cb = ft ? c1v1 : c1v0;
#pragma unroll
        for (int reg = 0; reg < 4; ++reg) {
          const int p = wr * 32 + pt * 16 + (lane >> 4) * 4 + reg;
          const float vv = relu_f(acc[pt][ft][reg] + cb);
          unsigned hh, ll;
          split3(vv, hh, ll);
          H[p * 128 + ((cc ^ (p & 7)) << 2) + (fo & 3)] = (hh << 16) | ll;
        }
      }
    __syncthreads();  // H ready

    // ---- g2: acc2 = h2 . W2^T (bf16x3), A from H ----
    f32x4 acc2[2][2];
#pragma unroll
    for (int pt = 0; pt < 2; ++pt)
#pragma unroll
      for (int ft = 0; ft < 2; ++ft) acc2[pt][ft] = (f32x4){0.f, 0.f, 0.f, 0.f};
#pragma unroll
    for (int ks = 0; ks < 4; ++ks) {
      const int cc0 = ks * 8 + (lane >> 4) * 2;
#pragma unroll
      for (int pt = 0; pt < 2; ++pt) {
        const int p = wr * 32 + pt * 16 + (lane & 15);
        const int4 u0 = *(const int4*)&H[p * 128 + ((cc0 ^ (p & 7)) << 2)];
        const int4 u1 = *(const int4*)&H[p * 128 + (((cc0 + 1) ^ (p & 7)) << 2)];
        const unsigned uu[8] = {(unsigned)u0.x, (unsigned)u0.y, (unsigned)u0.z,
                                (unsigned)u0.w, (unsigned)u1.x, (unsigned)u1.y,
                                (unsigned)u1.z, (unsigned)u1.w};
        short8v ah, al;
#pragma unroll
        for (int e = 0; e < 8; ++e) {
          ah[e] = (short)(uu[e] >> 16);
          al[e] = (short)(uu[e] & 0xFFFFu);
        }
#pragma unroll
        for (int ft = 0; ft < 2; ++ft) {
          acc2[pt][ft] = mfma16x16x32bf(al, w2h[ft][ks], acc2[pt][ft]);
          acc2[pt][ft] = mfma16x16x32bf(ah, w2l[ft][ks], acc2[pt][ft]);
          acc2[pt][ft] = mfma16x16x32bf(ah, w2h[ft][ks], acc2[pt][ft]);
        }
      }
    }
    __syncthreads();  // H reads done (next iter may overwrite H)

    // ---- g2 epilogue: relu+max over 8 pairs/query -> OS rows j*8.. ----
    {
      const int g = lane >> 4;
#pragma unroll
      for (int pt = 0; pt < 2; ++pt)
#pragma unroll
        for (int ft = 0; ft < 2; ++ft) {
          const int fo = wc * 32 + ft * 16 + (lane & 15);
          const float cb = ft ? c2v1 : c2v0;
          const float v0 = relu_f(acc2[pt][ft][0] + cb);
          const float v1 = relu_f(acc2[pt][ft][1] + cb);
          const float v2 = relu_f(acc2[pt][ft][2] + cb);
          const float v3 = relu_f(acc2[pt][ft][3] + cb);
          float m = fmaxf(fmaxf(v0, v1), fmaxf(v2, v3));
          m = fmaxf(m, __shfl_xor(m, 16, 64));
          if ((g & 1) == 0) {
            const int qloc = wr * 4 + pt * 2 + (g >> 1);
            OS[(j * 8 + qloc) * 128 + fo] = m;
          }
        }
    }

    // ---- pack & write A[j+1] into Anxt (loads returned during g2) ----
    if (j < 7) {
      float hv0[8] = {relu_f(a0.x - n0.x + c0a.x), relu_f(a0.y - n0.y + c0a.y),
                      relu_f(a0.z - n0.z + c0a.z), relu_f(a0.w - n0.w + c0a.w),
                      relu_f(a1.x - n1.x + c0b.x), relu_f(a1.y - n1.y + c0b.y),
                      relu_f(a1.z - n1.z + c0b.z), relu_f(a1.w - n1.w + c0b.w)};
      float hv1[8] = {relu_f(a2.x - n2.x + c0c.x), relu_f(a2.y - n2.y + c0c.y),
                      relu_f(a2.z - n2.z + c0c.z), relu_f(a2.w - n2.w + c0c.w),
                      relu_f(a3.x - n3.x + c0d.x), relu_f(a3.y - n3.y + c0d.y),
                      relu_f(a3.z - n3.z + c0d.z), relu_f(a3.w - n3.w + c0d.w)};
      PACK_WRITE_A(Anxt, hv0, part8 * 2)
      PACK_WRITE_A(Anxt, hv1, part8 * 2 + 1)
    }
    __syncthreads();  // A[j+1] ready; OS rows settled
  }

  // ---- final coalesced out-write: OS[64][128] -> out[bb][f][qseg*64..] ----
  {
    const int f = t >> 2, seg = t & 3;
    float* __restrict__ op = out + (long)(bb * 128 + f) * 2048 + qseg * 64 + seg * 16;
#pragma unroll
    for (int u = 0; u < 4; ++u) {
      float4 o;
      o.x = OS[(seg * 16 + u * 4 + 0) * 128 + f];
      o.y = OS[(seg * 16 + u * 4 + 1) * 128 + f];
      o.z = OS[(seg * 16 + u * 4 + 2) * 128 + f];
      o.w = OS[(seg * 16 + u * 4 + 3) * 128 + f];
      *(float4*)(op + u * 4) = o;
    }
  }
}

// ------------------------------- launch ------------------------------------
extern "C" void kernel_launch(void* const* d_in, const int* in_sizes, int n_in,
                              void* d_out, int out_size, void* d_ws,
                              size_t ws_size, hipStream_t stream) {
  (void)in_sizes; (void)n_in; (void)out_size; (void)ws_size;
  const float* x = (const float*)d_in[0];
  const float* w0 = (const float*)d_in[1];
  const float* b0 = (const float*)d_in[2];
  const float* wst = (const float*)d_in[3];
  const float* bst = (const float*)d_in[4];
  const float* g = (const float*)d_in[5];
  const float* be = (const float*)d_in[6];
  const float* bm = (const float*)d_in[7];
  const float* bv = (const float*)d_in[8];
  float* out = (float*)d_out;
  float* ws = (float*)d_ws;

  hipFuncSetAttribute((const void*)fused_kernel,
                      hipFuncAttributeMaxDynamicSharedMemorySize, 131072);

  prep_kernel<<<64, 256, 0, stream>>>(w0, b0, wst, bst, g, be, bm, bv, ws);
  y_kernel<<<NQ * DIMF / 256, 256, 0, stream>>>(x, ws);
  knn_part_kernel<<<1024, 256, 0, stream>>>(x, ws);
  knn_merge_kernel<<<NQ / 64, 64, 0, stream>>>(ws);
  fused_kernel<<<256, 512, 131072, stream>>>(ws, out);
}